// Round 6
// baseline (638.659 us; speedup 1.0000x reference)
//
#include <hip/hip_runtime.h>
#include <stdint.h>
#include <stddef.h>

typedef int i32x4 __attribute__((ext_vector_type(4)));
typedef int i32x2 __attribute__((ext_vector_type(2)));

// ---------------- workspace layout (bytes) ----------------
#define WS_WFRAG   0u          // 262144  w_hh int8, [w8][t8][ks4][lane64][16]
#define WS_WIH     262144u     // 131072  w_ih int8 [1024][128]
#define WS_BIASHH  393216u     // 4096    b_hh_int*256 as i32 [1024]
#define WS_BIASIH  397312u     // 4096    b_ih_int*256 as i32 [1024]
#define WS_WLIN    401408u     // 1024    w_lin int i32 [256]
#define WS_BLIN    402432u     // 4       b_lin int
#define WS_HSTATE  409600u     // 256 wg * 512 = 131072 (h planes)
#define WS_CSTATE  540672u     // 256*512*4 = 524288 (c per lane)
#define WS_GI      1064960u    // cs * 524288 bytes (chunk-local step ring)

#define MFMA_I8(a,b,c) __builtin_amdgcn_mfma_i32_16x16x64_i8(a,b,c,0,0,0)
#define RHE8(x) ((((x) + 127) + (((x) >> 8) & 1)) >> 8)

// LDS-drain-only barrier: keeps global prefetch loads in flight across steps.
#define BAR() do { asm volatile("s_waitcnt lgkmcnt(0)" ::: "memory"); \
                   __builtin_amdgcn_s_barrier(); } while (0)

__device__ __forceinline__ float clamp3(float x, float lo, float hi) {
    return __builtin_amdgcn_fmed3f(x, lo, hi);
}
__device__ __forceinline__ float q16f(float x) {
    return clamp3(__builtin_rintf(x * 256.0f), -32768.0f, 32767.0f);
}
__device__ __forceinline__ int iclamp(int v, int lo, int hi) {
    return v < lo ? lo : (v > hi ? hi : v);
}

// ---------------- prep: quantize weights into fragment layouts ----------------
__global__ void prep_kernel(const float* __restrict__ wih, const float* __restrict__ whh,
                            const float* __restrict__ bih, const float* __restrict__ bhh,
                            const float* __restrict__ wlin, const float* __restrict__ blin,
                            uint8_t* __restrict__ ws) {
    int tid = blockIdx.x * blockDim.x + threadIdx.x;   // 262144 threads
    {   // w_hh -> A-fragment order: [w][t8][ks][lane][16B]
        int p = tid;
        int j = p & 15, lane = (p >> 4) & 63, ks = (p >> 10) & 3, t8 = (p >> 12) & 7, w = (p >> 15) & 7;
        int row = (t8 >> 1) * 256 + w * 32 + (t8 & 1) * 16 + (lane & 15);
        int k = ks * 64 + (lane >> 4) * 16 + j;
        int v = (int)q16f(whh[row * 256 + k]);
        v = iclamp(v, -127, 127);
        ((int8_t*)(ws + WS_WFRAG))[p] = (int8_t)v;
    }
    if (tid < 131072) {  // w_ih plain [gcol][k] int8
        int gcol = tid >> 7, k = tid & 127;
        int v = (int)q16f(wih[gcol * 128 + k]);
        v = iclamp(v, -127, 127);
        ((int8_t*)(ws + WS_WIH))[tid] = (int8_t)v;
    }
    if (tid < 1024) {    // biases scaled to 2^-16 units (i32)
        ((int*)(ws + WS_BIASHH))[tid] = ((int)q16f(bhh[tid])) * 256;
        ((int*)(ws + WS_BIASIH))[tid] = ((int)q16f(bih[tid])) * 256;
    }
    if (tid < 256) ((int*)(ws + WS_WLIN))[tid] = (int)q16f(wlin[tid]);
    if (tid == 0)  ((int*)(ws + WS_BLIN))[0]   = (int)q16f(blin[0]);
}

// ---------------- gi = quant(xq @ w_ih_q^T + b_ih_q), stored per-lane slot order ----------
__launch_bounds__(512, 2)
__global__ void gi_kernel(const float* __restrict__ x, uint8_t* __restrict__ ws, int t0) {
    __shared__ uint8_t xa[2048], xb[2048];   // x hi/lo i8 planes [16 rows][128 k], swizzled
    int tid = threadIdx.x;
    int wgr = blockIdx.x;          // batch group of 16, 0..15
    int tl  = blockIdx.y;          // chunk-local step  (ring index!)
    int t   = t0 + tl;             // global step (x read only)
    {   // stage + quantize + split x (x = 128a + b)
        int row = tid >> 5, c4 = (tid & 31) * 4;
        int b = wgr * 16 + row;
        const float4 xv = *(const float4*)(x + ((size_t)b * 512 + t) * 128 + c4);
        int v0 = (int)q16f(xv.x), v1 = (int)q16f(xv.y), v2 = (int)q16f(xv.z), v3 = (int)q16f(xv.w);
        uint32_t da = ((uint32_t)((v0 >> 7) & 255)) | ((uint32_t)((v1 >> 7) & 255) << 8) |
                      ((uint32_t)((v2 >> 7) & 255) << 16) | ((uint32_t)((v3 >> 7) & 255) << 24);
        uint32_t db = ((uint32_t)(v0 & 127)) | ((uint32_t)(v1 & 127) << 8) |
                      ((uint32_t)(v2 & 127) << 16) | ((uint32_t)(v3 & 127) << 24);
        int addr = row * 128 + (((c4 >> 4) ^ (row & 7)) * 16) + (c4 & 15);
        *(uint32_t*)(xa + addr) = da;
        *(uint32_t*)(xb + addr) = db;
    }
    __syncthreads();
    int wid = tid >> 6, lane = tid & 63, lr = lane & 15, lg = lane >> 4;
    const uint8_t* wq = ws + WS_WIH;
    i32x4 af[8][2];
#pragma unroll
    for (int mt = 0; mt < 8; ++mt) {
        int gcol = (mt >> 1) * 256 + wid * 32 + (mt & 1) * 16 + lr;
#pragma unroll
        for (int kt = 0; kt < 2; ++kt)
            af[mt][kt] = *(const i32x4*)(wq + gcol * 128 + kt * 64 + lg * 16);
    }
    i32x4 bha[2], bhb[2];
#pragma unroll
    for (int kt = 0; kt < 2; ++kt) {
        int addr = lr * 128 + ((((kt * 4) + lg) ^ (lr & 7)) * 16);
        bha[kt] = *(const i32x4*)(xa + addr);
        bhb[kt] = *(const i32x4*)(xb + addr);
    }
    i32x4 acch[8], accl[8];
    const int* bi = (const int*)(ws + WS_BIASIH);
#pragma unroll
    for (int mt = 0; mt < 8; ++mt) {
        i32x4 z = {0, 0, 0, 0};
        int gb = (mt >> 1) * 256 + wid * 32 + (mt & 1) * 16 + lg * 4;
        i32x4 bc = *(const i32x4*)(bi + gb);
        acch[mt] = MFMA_I8(af[mt][0], bha[0], z);
        accl[mt] = MFMA_I8(af[mt][0], bhb[0], bc);   // bias folded into C (enters v once)
        acch[mt] = MFMA_I8(af[mt][1], bha[1], acch[mt]);
        accl[mt] = MFMA_I8(af[mt][1], bhb[1], accl[mt]);
    }
    // quantize (exact RHE)
    int gq[8][4];
#pragma unroll
    for (int mt = 0; mt < 8; ++mt)
#pragma unroll
        for (int rr = 0; rr < 4; ++rr) {
            int v = acch[mt][rr] * 128 + accl[mt][rr];
            gq[mt][rr] = iclamp(RHE8(v), -32768, 32767);
        }
    // scatter to recur slot order: WG = batch; lane bits gsel|cp<<1|mm<<2|X<<3|sg<<4
    // dword(gsel) = g[G=gsel] | g[G=gsel+2]<<16 ; cp=rr&1, X=rr>>1, sg=lg
    unsigned batch = (unsigned)(wgr * 16 + lr);
#pragma unroll
    for (int mm2 = 0; mm2 < 2; ++mm2)
#pragma unroll
        for (int rr2 = 0; rr2 < 4; ++rr2) {
            i32x2 outv;
            outv[0] = (gq[mm2][rr2] & 0xFFFF)     | (gq[4 + mm2][rr2] << 16);  // gsel=0: G0|G2
            outv[1] = (gq[2 + mm2][rr2] & 0xFFFF) | (gq[6 + mm2][rr2] << 16);  // gsel=1: G1|G3
            int Lp = ((rr2 & 1) << 1) | (mm2 << 2) | ((rr2 >> 1) << 3) | (lg << 4);
            *(i32x2*)(ws + WS_GI + (size_t)tl * 524288u +
                      (size_t)((batch * 8u + (unsigned)wid) * 64u + (unsigned)Lp) * 4u) = outv;
        }
}

// ---------------- recurrence: 256 WGs x 1 batch row, W_hh resident in registers ----------
// lane bits: 0=gsel(G-half), 1=cp(plane/k bit0), 2=mm(k bit4), 3=X(k bit1), 4-5=sg(k bits2-3)
// k_own = w*32 + mm*16 + sg*4 + 2X + cp ; slots: G=gsel and G=gsel+2 at k_own
__launch_bounds__(512, 2)
__global__ void recur_kernel(uint8_t* __restrict__ ws, float* __restrict__ out, int t0, int cs) {
    __shared__ __align__(16) uint8_t hbuf[2][512];    // [dbuf][plane(2)][256 k]
    __shared__ unsigned short lut[1544];              // quant(hard_sigmoid) LUT, u in [0,1536]
    __shared__ long long redl[8];
    int tid = threadIdx.x, w = tid >> 6, lane = tid & 63;
    int wb = blockIdx.x;                              // batch row
    int gsel = lane & 1;
    int cp   = (lane >> 1) & 1;
    int mm   = (lane >> 2) & 1;
    int X    = (lane >> 3) & 1;
    int sg   = lane >> 4;
    uint8_t* hb0 = &hbuf[0][0];

    // sigmoid LUT built with the EXACT fp64 expression the np reference evaluates
    for (int u = tid; u < 1537; u += 512) {
        double y = ((double)(u - 768) / 256.0) / 6.0 + 0.5;
        y = y < 0.0 ? 0.0 : (y > 1.0 ? 1.0 : y);
        lut[u] = (unsigned short)(int)__builtin_rint(y * 256.0);
    }

    // W_hh fragments -> registers (persistent across all steps)
    i32x4 wf[8][4];
#pragma unroll
    for (int t8 = 0; t8 < 8; ++t8)
#pragma unroll
        for (int ks = 0; ks < 4; ++ks)
            wf[t8][ks] = *(const i32x4*)(ws + WS_WFRAG + (((unsigned)(w * 8 + t8) * 4 + ks) << 10) + lane * 16);

    // static per-lane addresses (B cols: plane = (lane>>1)&1; 2-way bank alias = free)
    int addrB[4];
#pragma unroll
    for (int ks = 0; ks < 4; ++ks)
        addrB[ks] = cp * 256 + ks * 64 + sg * 16;

    int k_own = w * 32 + mm * 16 + sg * 4 + 2 * X + cp;
    int addrW = (gsel ? 256 : 0) + k_own;             // one byte-write per lane
    int biasP[2], wlv;
    {
        const int* bhh256 = (const int*)(ws + WS_BIASHH);
        int G0 = gsel, G1 = gsel + 2;
        biasP[0] = bhh256[G0 * 256 + k_own] + 768 * 256;               // G0/G1: sigmoid pre-bias
        biasP[1] = bhh256[G1 * 256 + k_own] + (G1 == 2 ? 0 : 768 * 256); // G2 tanh: none
        wlv = ((const int*)(ws + WS_WLIN))[k_own];
    }
    size_t gioff = (size_t)((unsigned)wb * 8u + (unsigned)w) * 256u + (unsigned)lane * 4u;

    uint8_t* hst = ws + WS_HSTATE + (unsigned)wb * 512u;
    int* cst = (int*)(ws + WS_CSTATE) + (unsigned)wb * 512u + (unsigned)tid;

    int c_;
    if (t0 == 0) {
        c_ = 0;
        if (tid < 128) *(uint32_t*)(hb0 + tid * 4) = 0u;
    } else {
        c_ = *cst;
        if (tid < 128) *(uint32_t*)(hb0 + tid * 4) = *(const uint32_t*)(hst + tid * 4);
    }
    // prefetch gi for step 0 (stays in VGPRs across the barrier)
    int gcur = *(const int*)(ws + WS_GI + gioff);
    int gnx;
    __syncthreads();

    int hl_ = 0;
    const i32x4 zerov = {0, 0, 0, 0};

    // PLANEPAIR: u = acc[t8][2X], v = acc[t8][2X+1] with t8 = gsel?(mm?T3:T2):(mm?T1:T0)
#define PLANEPAIR(T0, T1, T2, T3, U, V)                                                \
    int U, V;                                                                          \
    {                                                                                  \
        int ua = X ? acc[T0][2] : acc[T0][0], va = X ? acc[T0][3] : acc[T0][1];        \
        int ub = X ? acc[T1][2] : acc[T1][0], vb = X ? acc[T1][3] : acc[T1][1];        \
        int uc = X ? acc[T2][2] : acc[T2][0], vc = X ? acc[T2][3] : acc[T2][1];        \
        int ud = X ? acc[T3][2] : acc[T3][0], vd = X ? acc[T3][3] : acc[T3][1];        \
        int u0 = mm ? ub : ua, v0 = mm ? vb : va;                                      \
        int u1 = mm ? ud : uc, v1 = mm ? vd : vc;                                      \
        U = gsel ? u1 : u0;                                                            \
        V = gsel ? v1 : v0;                                                            \
    }
    // SLOT: plane combine via partner lane^2 (one swizzle); d = 4*a + b
#define SLOT(U, V, BIAS, OUTG)                                                         \
    int OUTG;                                                                          \
    {                                                                                  \
        int own = cp ? V : U;                                                          \
        int snd = cp ? U : V;                                                          \
        int z = __builtin_amdgcn_ds_swizzle(snd, 0x081F);                              \
        int hi = cp ? z : own;                                                         \
        int lo = cp ? own : z;                                                         \
        OUTG = RHE8(hi * 4 + lo + (BIAS));                                             \
    }
#define STEP(PP, GUSE, GPRE, TPRE)                                                     \
    {                                                                                  \
        GPRE = *(const int*)(ws + WS_GI + (size_t)(TPRE) * 524288u + gioff);           \
        i32x4 acc[8];                                                                  \
        _Pragma("unroll")                                                              \
        for (int ks = 0; ks < 4; ++ks) {                                               \
            i32x4 bf = *(const i32x4*)(hb0 + (PP) * 512 + addrB[ks]);                  \
            _Pragma("unroll")                                                          \
            for (int t8 = 0; t8 < 8; ++t8)                                             \
                acc[t8] = (ks == 0) ? MFMA_I8(wf[t8][0], bf, zerov)                    \
                                    : MFMA_I8(wf[t8][ks], bf, acc[t8]);                \
        }                                                                              \
        PLANEPAIR(0, 1, 2, 3, uA, vA)                                                  \
        PLANEPAIR(4, 5, 6, 7, uB, vB)                                                  \
        SLOT(uA, vA, biasP[0], gA)                                                     \
        SLOT(uB, vB, biasP[1], gB)                                                     \
        int givlo = ((GUSE) << 16) >> 16, givhi = (GUSE) >> 16;                        \
        int first = (int)lut[iclamp(gA + givlo, 0, 1536)];    /* gsel0: i, gsel1: f */ \
        int lutB  = (int)lut[iclamp(gB + givhi, 0, 1536)];                             \
        int clpB  = iclamp(gB - 768 * 0 + givhi, -256, 256);  /* tanh path (no pre) */ \
        int second = gsel ? lutB : clpB;                      /* gsel0: c, gsel1: o */ \
        int z1 = __builtin_amdgcn_ds_swizzle(first, 0x041F);                           \
        int z2 = __builtin_amdgcn_ds_swizzle(second, 0x041F);                          \
        int i_g = gsel ? z1 : first;                                                   \
        int f_g = gsel ? first : z1;                                                   \
        int c_g = gsel ? z2 : second;                                                  \
        int o_g = gsel ? second : z2;                                                  \
        int fcq = RHE8(__mul24(f_g, c_));                                              \
        int icq = RHE8(__mul24(i_g, c_g));                                             \
        int cn  = iclamp(fcq + icq, -32768, 32767);                                    \
        c_ = cn;                                                                       \
        int th = iclamp(cn, -256, 256);                                                \
        int hq = RHE8(__mul24(o_g, th));                                               \
        *(int8_t*)(hb0 + ((PP) ^ 1) * 512 + addrW) = (int8_t)(gsel ? (hq & 3) : (hq >> 2)); \
        hl_ = hq;                                                                      \
        BAR();                                                                         \
    }

    for (int tl = 0; tl < cs; tl += 2) {
        int tn2 = (tl + 2 < cs) ? tl + 2 : 0;   // harmless wrap on last iter
        STEP(0, gcur, gnx, tl + 1)
        STEP(1, gnx, gcur, tn2)
    }
#undef STEP
#undef SLOT
#undef PLANEPAIR

    // save state for next chunk (final buffer parity is 0 since cs is even)
    if (tid < 128) *(uint32_t*)(hst + tid * 4) = *(const uint32_t*)(hb0 + tid * 4);
    *cst = c_;

    if (t0 + cs == 512) {   // head: out = quant(h_last @ w_lin^T + b_lin), exact int64
        long long s = gsel ? 0LL : (long long)hl_ * (long long)wlv;
        s += __shfl_xor(s, 1);
        s += __shfl_xor(s, 2);
        s += __shfl_xor(s, 4);
        s += __shfl_xor(s, 8);
        s += __shfl_xor(s, 16);
        s += __shfl_xor(s, 32);
        if (lane == 0) redl[w] = s;
        __syncthreads();
        if (tid == 0) {
            long long tot = 0;
#pragma unroll
            for (int ww = 0; ww < 8; ++ww) tot += redl[ww];
            tot += 256LL * (long long)((const int*)(ws + WS_BLIN))[0];
            long long q = ((tot + 127) + ((tot >> 8) & 1)) >> 8;
            q = q < -32768 ? -32768 : (q > 32767 ? 32767 : q);
            out[wb] = (float)q * 0.00390625f;
        }
    }
}

// ---------------- host ----------------
extern "C" void kernel_launch(void* const* d_in, const int* in_sizes, int n_in,
                              void* d_out, int out_size, void* d_ws, size_t ws_size,
                              hipStream_t stream) {
    const float* x    = (const float*)d_in[0];
    const float* wih  = (const float*)d_in[1];
    const float* whh  = (const float*)d_in[2];
    const float* bih  = (const float*)d_in[3];
    const float* bhh  = (const float*)d_in[4];
    const float* wlin = (const float*)d_in[5];
    const float* blin = (const float*)d_in[6];
    float* out = (float*)d_out;
    uint8_t* ws = (uint8_t*)d_ws;

    prep_kernel<<<512, 512, 0, stream>>>(wih, whh, bih, bhh, wlin, blin, ws);

    int cs = 512;
    while ((size_t)WS_GI + (size_t)cs * 524288u > ws_size && cs > 8) cs >>= 1;

    for (int t0 = 0; t0 < 512; t0 += cs) {
        gi_kernel<<<dim3(16, cs), 512, 0, stream>>>(x, ws, t0);
        recur_kernel<<<256, 512, 0, stream>>>(ws, out, t0, cs);
    }
}

// Round 7
// 576.533 us; speedup vs baseline: 1.1078x; 1.1078x over previous
//
#include <hip/hip_runtime.h>
#include <stdint.h>
#include <stddef.h>

typedef int i32x4 __attribute__((ext_vector_type(4)));
typedef int i32x2 __attribute__((ext_vector_type(2)));

// ---------------- workspace layout (bytes) ----------------
#define WS_WFRAG   0u          // 262144  w_hh int8, [w8][t8][ks4][lane64][16]
#define WS_WIH     262144u     // 131072  w_ih int8 [1024][128]
#define WS_BIASHH  393216u     // 4096    b_hh_int*256 as i32 [1024]
#define WS_BIASIH  397312u     // 4096    b_ih_int*256 as i32 [1024]
#define WS_WLIN    401408u     // 1024    w_lin int i32 [256]
#define WS_BLIN    402432u     // 4       b_lin int
#define WS_HSTATE  409600u     // 256 wg * 512 = 131072 (h planes)
#define WS_CSTATE  540672u     // 256*512*4 = 524288 (c per lane)
#define WS_GI      1064960u    // cs * 524288 bytes (chunk-local step ring)

#define MFMA_I8(a,b,c) __builtin_amdgcn_mfma_i32_16x16x64_i8(a,b,c,0,0,0)
#define RHE8(x) ((((x) + 127) + (((x) >> 8) & 1)) >> 8)

// cross-lane xor1 / xor2 via DPP quad_perm (VALU pipe — replaces ds_swizzle)
#define DPPX1(v) __builtin_amdgcn_update_dpp(0, (v), 0xB1, 0xF, 0xF, true)  // [1,0,3,2]
#define DPPX2(v) __builtin_amdgcn_update_dpp(0, (v), 0x4E, 0xF, 0xF, true)  // [2,3,0,1]

// LDS-drain-only barrier: keeps global prefetch loads in flight across steps.
#define BAR() do { asm volatile("s_waitcnt lgkmcnt(0)" ::: "memory"); \
                   __builtin_amdgcn_s_barrier(); } while (0)

__device__ __forceinline__ float clamp3(float x, float lo, float hi) {
    return __builtin_amdgcn_fmed3f(x, lo, hi);
}
__device__ __forceinline__ float q16f(float x) {
    return clamp3(__builtin_rintf(x * 256.0f), -32768.0f, 32767.0f);
}
__device__ __forceinline__ int iclamp(int v, int lo, int hi) {
    return v < lo ? lo : (v > hi ? hi : v);
}
// exact round-half-even of u/6 for u in [0,1536] (== np's fp64 quant(hard_sigmoid) path,
// proven: tie inputs are dyadic-exact in fp64 so rint applies half-even; non-ties >= 1/6 away)
__device__ __forceinline__ int sigq(int u) {
    int q = __mul24(u, 43691) >> 18;       // exact floor(u/6) for u <= 1536
    int r = u - __mul24(q, 6);
    return q + (((r + (q & 1)) > 3) ? 1 : 0);
}

// ---------------- prep: quantize weights into fragment layouts ----------------
__global__ void prep_kernel(const float* __restrict__ wih, const float* __restrict__ whh,
                            const float* __restrict__ bih, const float* __restrict__ bhh,
                            const float* __restrict__ wlin, const float* __restrict__ blin,
                            uint8_t* __restrict__ ws) {
    int tid = blockIdx.x * blockDim.x + threadIdx.x;   // 262144 threads
    {   // w_hh -> A-fragment order: [w][t8][ks][lane][16B]
        int p = tid;
        int j = p & 15, lane = (p >> 4) & 63, ks = (p >> 10) & 3, t8 = (p >> 12) & 7, w = (p >> 15) & 7;
        int row = (t8 >> 1) * 256 + w * 32 + (t8 & 1) * 16 + (lane & 15);
        int k = ks * 64 + (lane >> 4) * 16 + j;
        int v = (int)q16f(whh[row * 256 + k]);
        v = iclamp(v, -127, 127);
        ((int8_t*)(ws + WS_WFRAG))[p] = (int8_t)v;
    }
    if (tid < 131072) {  // w_ih plain [gcol][k] int8
        int gcol = tid >> 7, k = tid & 127;
        int v = (int)q16f(wih[gcol * 128 + k]);
        v = iclamp(v, -127, 127);
        ((int8_t*)(ws + WS_WIH))[tid] = (int8_t)v;
    }
    if (tid < 1024) {    // biases scaled to 2^-16 units (i32)
        ((int*)(ws + WS_BIASHH))[tid] = ((int)q16f(bhh[tid])) * 256;
        ((int*)(ws + WS_BIASIH))[tid] = ((int)q16f(bih[tid])) * 256;
    }
    if (tid < 256) ((int*)(ws + WS_WLIN))[tid] = (int)q16f(wlin[tid]);
    if (tid == 0)  ((int*)(ws + WS_BLIN))[0]   = (int)q16f(blin[0]);
}

// ---------------- gi = quant(xq @ w_ih_q^T + b_ih_q), stored per-lane slot order ----------
__launch_bounds__(512, 2)
__global__ void gi_kernel(const float* __restrict__ x, uint8_t* __restrict__ ws, int t0) {
    __shared__ uint8_t xa[2048], xb[2048];   // x hi/lo i8 planes [16 rows][128 k], swizzled
    int tid = threadIdx.x;
    int wgr = blockIdx.x;          // batch group of 16, 0..15
    int tl  = blockIdx.y;          // chunk-local step  (ring index!)
    int t   = t0 + tl;             // global step (x read only)
    {   // stage + quantize + split x (x = 128a + b)
        int row = tid >> 5, c4 = (tid & 31) * 4;
        int b = wgr * 16 + row;
        const float4 xv = *(const float4*)(x + ((size_t)b * 512 + t) * 128 + c4);
        int v0 = (int)q16f(xv.x), v1 = (int)q16f(xv.y), v2 = (int)q16f(xv.z), v3 = (int)q16f(xv.w);
        uint32_t da = ((uint32_t)((v0 >> 7) & 255)) | ((uint32_t)((v1 >> 7) & 255) << 8) |
                      ((uint32_t)((v2 >> 7) & 255) << 16) | ((uint32_t)((v3 >> 7) & 255) << 24);
        uint32_t db = ((uint32_t)(v0 & 127)) | ((uint32_t)(v1 & 127) << 8) |
                      ((uint32_t)(v2 & 127) << 16) | ((uint32_t)(v3 & 127) << 24);
        int addr = row * 128 + (((c4 >> 4) ^ (row & 7)) * 16) + (c4 & 15);
        *(uint32_t*)(xa + addr) = da;
        *(uint32_t*)(xb + addr) = db;
    }
    __syncthreads();
    int wid = tid >> 6, lane = tid & 63, lr = lane & 15, lg = lane >> 4;
    const uint8_t* wq = ws + WS_WIH;
    i32x4 af[8][2];
#pragma unroll
    for (int mt = 0; mt < 8; ++mt) {
        int gcol = (mt >> 1) * 256 + wid * 32 + (mt & 1) * 16 + lr;
#pragma unroll
        for (int kt = 0; kt < 2; ++kt)
            af[mt][kt] = *(const i32x4*)(wq + gcol * 128 + kt * 64 + lg * 16);
    }
    i32x4 bha[2], bhb[2];
#pragma unroll
    for (int kt = 0; kt < 2; ++kt) {
        int addr = lr * 128 + ((((kt * 4) + lg) ^ (lr & 7)) * 16);
        bha[kt] = *(const i32x4*)(xa + addr);
        bhb[kt] = *(const i32x4*)(xb + addr);
    }
    i32x4 acch[8], accl[8];
    const int* bi = (const int*)(ws + WS_BIASIH);
#pragma unroll
    for (int mt = 0; mt < 8; ++mt) {
        i32x4 z = {0, 0, 0, 0};
        int gb = (mt >> 1) * 256 + wid * 32 + (mt & 1) * 16 + lg * 4;
        i32x4 bc = *(const i32x4*)(bi + gb);
        acch[mt] = MFMA_I8(af[mt][0], bha[0], z);
        accl[mt] = MFMA_I8(af[mt][0], bhb[0], bc);   // bias folded into C (enters v once)
        acch[mt] = MFMA_I8(af[mt][1], bha[1], acch[mt]);
        accl[mt] = MFMA_I8(af[mt][1], bhb[1], accl[mt]);
    }
    // quantize (exact RHE)
    int gq[8][4];
#pragma unroll
    for (int mt = 0; mt < 8; ++mt)
#pragma unroll
        for (int rr = 0; rr < 4; ++rr) {
            int v = acch[mt][rr] * 128 + accl[mt][rr];
            gq[mt][rr] = iclamp(RHE8(v), -32768, 32767);
        }
    // scatter to recur slot order: WG = batch; lane bits gsel|cp<<1|mm<<2|X<<3|sg<<4
    // dword(gsel) = g[G=gsel] | g[G=gsel+2]<<16 ; cp=rr&1, X=rr>>1, sg=lg
    unsigned batch = (unsigned)(wgr * 16 + lr);
#pragma unroll
    for (int mm2 = 0; mm2 < 2; ++mm2)
#pragma unroll
        for (int rr2 = 0; rr2 < 4; ++rr2) {
            i32x2 outv;
            outv[0] = (gq[mm2][rr2] & 0xFFFF)     | (gq[4 + mm2][rr2] << 16);  // gsel=0: G0|G2
            outv[1] = (gq[2 + mm2][rr2] & 0xFFFF) | (gq[6 + mm2][rr2] << 16);  // gsel=1: G1|G3
            int Lp = ((rr2 & 1) << 1) | (mm2 << 2) | ((rr2 >> 1) << 3) | (lg << 4);
            *(i32x2*)(ws + WS_GI + (size_t)tl * 524288u +
                      (size_t)((batch * 8u + (unsigned)wid) * 64u + (unsigned)Lp) * 4u) = outv;
        }
}

// ---------------- recurrence: 256 WGs x 1 batch row, W_hh resident in registers ----------
// lane bits: 0=gsel(G-half), 1=cp(plane/k bit0), 2=mm(k bit4), 3=X(k bit1), 4-5=sg(k bits2-3)
// k_own = w*32 + mm*16 + sg*4 + 2X + cp ; slots: G=gsel and G=gsel+2 at k_own
__launch_bounds__(512, 2)
__global__ void recur_kernel(uint8_t* __restrict__ ws, float* __restrict__ out, int t0, int cs) {
    __shared__ __align__(16) uint8_t hbuf[2][512];    // [dbuf][plane(2)][256 k]
    __shared__ long long redl[8];
    int tid = threadIdx.x, w = tid >> 6, lane = tid & 63;
    int wb = blockIdx.x;                              // batch row
    int gsel = lane & 1;
    int cp   = (lane >> 1) & 1;
    int mm   = (lane >> 2) & 1;
    int X    = (lane >> 3) & 1;
    int sg   = lane >> 4;
    uint8_t* hb0 = &hbuf[0][0];

    // W_hh fragments -> registers (persistent across all steps)
    i32x4 wf[8][4];
#pragma unroll
    for (int t8 = 0; t8 < 8; ++t8)
#pragma unroll
        for (int ks = 0; ks < 4; ++ks)
            wf[t8][ks] = *(const i32x4*)(ws + WS_WFRAG + (((unsigned)(w * 8 + t8) * 4 + ks) << 10) + lane * 16);

    // static per-lane addresses (B cols: plane = (lane>>1)&1; 2-way bank alias = free)
    int addrB[4];
#pragma unroll
    for (int ks = 0; ks < 4; ++ks)
        addrB[ks] = cp * 256 + ks * 64 + sg * 16;

    int k_own = w * 32 + mm * 16 + sg * 4 + 2 * X + cp;
    int addrW = (gsel ? 256 : 0) + k_own;             // one byte-write per lane
    int biasP[2], wlv;
    {
        const int* bhh256 = (const int*)(ws + WS_BIASHH);
        int G0 = gsel, G1 = gsel + 2;
        biasP[0] = bhh256[G0 * 256 + k_own] + 768 * 256;                 // G0/G1: sigmoid pre-bias
        biasP[1] = bhh256[G1 * 256 + k_own] + (G1 == 2 ? 0 : 768 * 256); // G2 tanh: none
        wlv = ((const int*)(ws + WS_WLIN))[k_own];
    }
    size_t gioff = (size_t)((unsigned)wb * 8u + (unsigned)w) * 256u + (unsigned)lane * 4u;

    uint8_t* hst = ws + WS_HSTATE + (unsigned)wb * 512u;
    int* cst = (int*)(ws + WS_CSTATE) + (unsigned)wb * 512u + (unsigned)tid;

    int c_;
    if (t0 == 0) {
        c_ = 0;
        if (tid < 128) *(uint32_t*)(hb0 + tid * 4) = 0u;
    } else {
        c_ = *cst;
        if (tid < 128) *(uint32_t*)(hb0 + tid * 4) = *(const uint32_t*)(hst + tid * 4);
    }
    // prefetch gi for step 0 (stays in VGPRs across the barrier)
    int gcur = *(const int*)(ws + WS_GI + gioff);
    int gnx;
    __syncthreads();

    int hl_ = 0;
    const i32x4 zerov = {0, 0, 0, 0};

    // PLANEPAIR: u = acc[t8][2X], v = acc[t8][2X+1] with t8 = gsel?(mm?T3:T2):(mm?T1:T0)
#define PLANEPAIR(T0, T1, T2, T3, U, V)                                                \
    int U, V;                                                                          \
    {                                                                                  \
        int ua = X ? acc[T0][2] : acc[T0][0], va = X ? acc[T0][3] : acc[T0][1];        \
        int ub = X ? acc[T1][2] : acc[T1][0], vb = X ? acc[T1][3] : acc[T1][1];        \
        int uc = X ? acc[T2][2] : acc[T2][0], vc = X ? acc[T2][3] : acc[T2][1];        \
        int ud = X ? acc[T3][2] : acc[T3][0], vd = X ? acc[T3][3] : acc[T3][1];        \
        int u0 = mm ? ub : ua, v0 = mm ? vb : va;                                      \
        int u1 = mm ? ud : uc, v1 = mm ? vd : vc;                                      \
        U = gsel ? u1 : u0;                                                            \
        V = gsel ? v1 : v0;                                                            \
    }
    // SLOT: plane combine via partner lane^2 (DPP quad_perm, no DS); d = 4*a + b
#define SLOT(U, V, BIAS, OUTG)                                                         \
    int OUTG;                                                                          \
    {                                                                                  \
        int own = cp ? V : U;                                                          \
        int snd = cp ? U : V;                                                          \
        int z = DPPX2(snd);                                                            \
        int hi = cp ? z : own;                                                         \
        int lo = cp ? own : z;                                                         \
        OUTG = RHE8(hi * 4 + lo + (BIAS));                                             \
    }
#define STEP(PP, GUSE, GPRE, TPRE)                                                     \
    {                                                                                  \
        GPRE = *(const int*)(ws + WS_GI + (size_t)(TPRE) * 524288u + gioff);           \
        i32x4 acc[8];                                                                  \
        _Pragma("unroll")                                                              \
        for (int ks = 0; ks < 4; ++ks) {                                               \
            i32x4 bf = *(const i32x4*)(hb0 + (PP) * 512 + addrB[ks]);                  \
            _Pragma("unroll")                                                          \
            for (int t8 = 0; t8 < 8; ++t8)                                             \
                acc[t8] = (ks == 0) ? MFMA_I8(wf[t8][0], bf, zerov)                    \
                                    : MFMA_I8(wf[t8][ks], bf, acc[t8]);                \
        }                                                                              \
        PLANEPAIR(0, 1, 2, 3, uA, vA)                                                  \
        PLANEPAIR(4, 5, 6, 7, uB, vB)                                                  \
        SLOT(uA, vA, biasP[0], gA)                                                     \
        SLOT(uB, vB, biasP[1], gB)                                                     \
        int givlo = ((GUSE) << 16) >> 16, givhi = (GUSE) >> 16;                        \
        int first = sigq(iclamp(gA + givlo, 0, 1536));        /* gsel0: i, gsel1: f */ \
        int sigB  = sigq(iclamp(gB + givhi, 0, 1536));                                 \
        int clpB  = iclamp(gB + givhi, -256, 256);            /* tanh path */          \
        int second = gsel ? sigB : clpB;                      /* gsel0: c, gsel1: o */ \
        int z1 = DPPX1(first);                                                         \
        int z2 = DPPX1(second);                                                        \
        int i_g = gsel ? z1 : first;                                                   \
        int f_g = gsel ? first : z1;                                                   \
        int c_g = gsel ? z2 : second;                                                  \
        int o_g = gsel ? second : z2;                                                  \
        int fcq = RHE8(__mul24(f_g, c_));                                              \
        int icq = RHE8(__mul24(i_g, c_g));                                             \
        int cn  = iclamp(fcq + icq, -32768, 32767);                                    \
        c_ = cn;                                                                       \
        int th = iclamp(cn, -256, 256);                                                \
        int hq = RHE8(__mul24(o_g, th));                                               \
        *(int8_t*)(hb0 + ((PP) ^ 1) * 512 + addrW) = (int8_t)(gsel ? (hq & 3) : (hq >> 2)); \
        hl_ = hq;                                                                      \
        BAR();                                                                         \
    }

    for (int tl = 0; tl < cs; tl += 2) {
        int tn2 = (tl + 2 < cs) ? tl + 2 : 0;   // harmless wrap on last iter
        STEP(0, gcur, gnx, tl + 1)
        STEP(1, gnx, gcur, tn2)
    }
#undef STEP
#undef SLOT
#undef PLANEPAIR

    // save state for next chunk (final buffer parity is 0 since cs is even)
    if (tid < 128) *(uint32_t*)(hst + tid * 4) = *(const uint32_t*)(hb0 + tid * 4);
    *cst = c_;

    if (t0 + cs == 512) {   // head: out = quant(h_last @ w_lin^T + b_lin), exact int64
        long long s = gsel ? 0LL : (long long)hl_ * (long long)wlv;
        s += __shfl_xor(s, 1);
        s += __shfl_xor(s, 2);
        s += __shfl_xor(s, 4);
        s += __shfl_xor(s, 8);
        s += __shfl_xor(s, 16);
        s += __shfl_xor(s, 32);
        if (lane == 0) redl[w] = s;
        __syncthreads();
        if (tid == 0) {
            long long tot = 0;
#pragma unroll
            for (int ww = 0; ww < 8; ++ww) tot += redl[ww];
            tot += 256LL * (long long)((const int*)(ws + WS_BLIN))[0];
            long long q = ((tot + 127) + ((tot >> 8) & 1)) >> 8;
            q = q < -32768 ? -32768 : (q > 32767 ? 32767 : q);
            out[wb] = (float)q * 0.00390625f;
        }
    }
}

// ---------------- host ----------------
extern "C" void kernel_launch(void* const* d_in, const int* in_sizes, int n_in,
                              void* d_out, int out_size, void* d_ws, size_t ws_size,
                              hipStream_t stream) {
    const float* x    = (const float*)d_in[0];
    const float* wih  = (const float*)d_in[1];
    const float* whh  = (const float*)d_in[2];
    const float* bih  = (const float*)d_in[3];
    const float* bhh  = (const float*)d_in[4];
    const float* wlin = (const float*)d_in[5];
    const float* blin = (const float*)d_in[6];
    float* out = (float*)d_out;
    uint8_t* ws = (uint8_t*)d_ws;

    prep_kernel<<<512, 512, 0, stream>>>(wih, whh, bih, bhh, wlin, blin, ws);

    int cs = 512;
    while ((size_t)WS_GI + (size_t)cs * 524288u > ws_size && cs > 8) cs >>= 1;

    for (int t0 = 0; t0 < 512; t0 += cs) {
        gi_kernel<<<dim3(16, cs), 512, 0, stream>>>(x, ws, t0);
        recur_kernel<<<256, 512, 0, stream>>>(ws, out, t0, cs);
    }
}

// Round 8
// 529.007 us; speedup vs baseline: 1.2073x; 1.0898x over previous
//
#include <hip/hip_runtime.h>
#include <stdint.h>
#include <stddef.h>

typedef int i32x4 __attribute__((ext_vector_type(4)));
typedef int i32x2 __attribute__((ext_vector_type(2)));

// ---------------- workspace layout (bytes) ----------------
#define WS_WFRAG   0u          // 262144  w_hh int8, [w8][t8][ks4][lane64][16]
#define WS_WIH     262144u     // 131072  w_ih int8 [1024][128]
#define WS_BIASHH  393216u     // 4096    b_hh_int*256 as i32 [1024]
#define WS_BIASIH  397312u     // 4096    b_ih_int*256 as i32 [1024]
#define WS_WLIN    401408u     // 1024    w_lin int i32 [256]
#define WS_BLIN    402432u     // 4       b_lin int
#define WS_HSTATE  409600u     // 256 wg * 512 = 131072 (h planes)
#define WS_CSTATE  540672u     // 256*512*4 = 524288 (c per lane)
#define WS_GI      1064960u    // cs * 524288 bytes (chunk-local step ring)

#define MFMA_I8(a,b,c) __builtin_amdgcn_mfma_i32_16x16x64_i8(a,b,c,0,0,0)
#define RHE8(x) ((((x) + 127) + (((x) >> 8) & 1)) >> 8)

// cross-lane exchanges on the VALU pipe (no DS unit)
#define DPPX1(v)   __builtin_amdgcn_update_dpp(0, (v), 0xB1, 0xF, 0xF, true)   // quad [1,0,3,2] = lane^1
#define DPPX2(v)   __builtin_amdgcn_update_dpp(0, (v), 0x4E, 0xF, 0xF, true)   // quad [2,3,0,1] = lane^2
#define DPPROR8(v) __builtin_amdgcn_update_dpp(0, (v), 0x128, 0xF, 0xF, true)  // row_ror:8 = lane^8

// LDS-drain-only barrier: keeps global prefetch loads in flight across steps.
#define BAR() do { asm volatile("s_waitcnt lgkmcnt(0)" ::: "memory"); \
                   __builtin_amdgcn_s_barrier(); } while (0)

__device__ __forceinline__ float clamp3(float x, float lo, float hi) {
    return __builtin_amdgcn_fmed3f(x, lo, hi);
}
__device__ __forceinline__ float q16f(float x) {
    return clamp3(__builtin_rintf(x * 256.0f), -32768.0f, 32767.0f);
}
__device__ __forceinline__ int iclamp(int v, int lo, int hi) {
    return v < lo ? lo : (v > hi ? hi : v);
}
// exact round-half-even of u/6 for u in [0,1536] (== np's fp64 quant(hard_sigmoid) path)
__device__ __forceinline__ int sigq(int u) {
    int q = __mul24(u, 43691) >> 18;       // exact floor(u/6) for u <= 1536
    int r = u - __mul24(q, 6);
    return q + (((r + (q & 1)) > 3) ? 1 : 0);
}

// ---------------- prep: quantize weights into fragment layouts ----------------
__global__ void prep_kernel(const float* __restrict__ wih, const float* __restrict__ whh,
                            const float* __restrict__ bih, const float* __restrict__ bhh,
                            const float* __restrict__ wlin, const float* __restrict__ blin,
                            uint8_t* __restrict__ ws) {
    int tid = blockIdx.x * blockDim.x + threadIdx.x;   // 262144 threads
    {   // w_hh -> A-fragment order: [w][t8][ks][lane][16B]
        int p = tid;
        int j = p & 15, lane = (p >> 4) & 63, ks = (p >> 10) & 3, t8 = (p >> 12) & 7, w = (p >> 15) & 7;
        int row = (t8 >> 1) * 256 + w * 32 + (t8 & 1) * 16 + (lane & 15);
        int k = ks * 64 + (lane >> 4) * 16 + j;
        int v = (int)q16f(whh[row * 256 + k]);
        v = iclamp(v, -127, 127);
        ((int8_t*)(ws + WS_WFRAG))[p] = (int8_t)v;
    }
    if (tid < 131072) {  // w_ih plain [gcol][k] int8
        int gcol = tid >> 7, k = tid & 127;
        int v = (int)q16f(wih[gcol * 128 + k]);
        v = iclamp(v, -127, 127);
        ((int8_t*)(ws + WS_WIH))[tid] = (int8_t)v;
    }
    if (tid < 1024) {    // biases scaled to 2^-16 units (i32)
        ((int*)(ws + WS_BIASHH))[tid] = ((int)q16f(bhh[tid])) * 256;
        ((int*)(ws + WS_BIASIH))[tid] = ((int)q16f(bih[tid])) * 256;
    }
    if (tid < 256) ((int*)(ws + WS_WLIN))[tid] = (int)q16f(wlin[tid]);
    if (tid == 0)  ((int*)(ws + WS_BLIN))[0]   = (int)q16f(blin[0]);
}

// ---------------- gi = quant(xq @ w_ih_q^T + b_ih_q), 4 steps per block ----------
__launch_bounds__(512, 2)
__global__ void gi_kernel(const float* __restrict__ x, uint8_t* __restrict__ ws, int t0) {
    __shared__ uint8_t xa[2][2048], xb[2][2048];   // x hi/lo i8 planes, double-buffered
    int tid = threadIdx.x;
    int wgr = blockIdx.x;              // batch group of 16, 0..15
    int tlb = blockIdx.y * 4;          // first of 4 chunk-local steps
    int wid = tid >> 6, lane = tid & 63, lr = lane & 15, lg = lane >> 4;

    // w_ih A-fragments + bias (loaded once, reused for 4 steps)
    const uint8_t* wq = ws + WS_WIH;
    i32x4 af[8][2];
#pragma unroll
    for (int mt = 0; mt < 8; ++mt) {
        int gcol = (mt >> 1) * 256 + wid * 32 + (mt & 1) * 16 + lr;
#pragma unroll
        for (int kt = 0; kt < 2; ++kt)
            af[mt][kt] = *(const i32x4*)(wq + gcol * 128 + kt * 64 + lg * 16);
    }
    i32x4 bcv[8];
    const int* bi = (const int*)(ws + WS_BIASIH);
#pragma unroll
    for (int mt = 0; mt < 8; ++mt) {
        int gb = (mt >> 1) * 256 + wid * 32 + (mt & 1) * 16 + lg * 4;
        bcv[mt] = *(const i32x4*)(bi + gb);
    }

    auto STAGE = [&](int tl, int buf) {
        int row = tid >> 5, c4 = (tid & 31) * 4;
        int b = wgr * 16 + row;
        const float4 xv = *(const float4*)(x + ((size_t)b * 512 + (t0 + tl)) * 128 + c4);
        int v0 = (int)q16f(xv.x), v1 = (int)q16f(xv.y), v2 = (int)q16f(xv.z), v3 = (int)q16f(xv.w);
        uint32_t da = ((uint32_t)((v0 >> 7) & 255)) | ((uint32_t)((v1 >> 7) & 255) << 8) |
                      ((uint32_t)((v2 >> 7) & 255) << 16) | ((uint32_t)((v3 >> 7) & 255) << 24);
        uint32_t db = ((uint32_t)(v0 & 127)) | ((uint32_t)(v1 & 127) << 8) |
                      ((uint32_t)(v2 & 127) << 16) | ((uint32_t)(v3 & 127) << 24);
        int addr = row * 128 + (((c4 >> 4) ^ (row & 7)) * 16) + (c4 & 15);
        *(uint32_t*)(&xa[buf][0] + addr) = da;
        *(uint32_t*)(&xb[buf][0] + addr) = db;
    };

    STAGE(tlb, 0);
    __syncthreads();

    for (int s4 = 0; s4 < 4; ++s4) {
        int tl = tlb + s4;
        if (s4 < 3) STAGE(tl + 1, (s4 + 1) & 1);
        int buf = s4 & 1;

        i32x4 bha[2], bhb[2];
#pragma unroll
        for (int kt = 0; kt < 2; ++kt) {
            int addr = lr * 128 + ((((kt * 4) + lg) ^ (lr & 7)) * 16);
            bha[kt] = *(const i32x4*)(&xa[buf][0] + addr);
            bhb[kt] = *(const i32x4*)(&xb[buf][0] + addr);
        }
        i32x4 acch[8], accl[8];
#pragma unroll
        for (int mt = 0; mt < 8; ++mt) {
            i32x4 z = {0, 0, 0, 0};
            acch[mt] = MFMA_I8(af[mt][0], bha[0], z);
            accl[mt] = MFMA_I8(af[mt][0], bhb[0], bcv[mt]);   // bias folded into C
            acch[mt] = MFMA_I8(af[mt][1], bha[1], acch[mt]);
            accl[mt] = MFMA_I8(af[mt][1], bhb[1], accl[mt]);
        }
        int gq[8][4];
#pragma unroll
        for (int mt = 0; mt < 8; ++mt)
#pragma unroll
            for (int rr = 0; rr < 4; ++rr) {
                int v = acch[mt][rr] * 128 + accl[mt][rr];
                gq[mt][rr] = iclamp(RHE8(v), -32768, 32767);
            }
        // scatter to recur slot order: WG = batch; lane bits gsel|cp<<1|mm<<2|X<<3|sg<<4
        unsigned batch = (unsigned)(wgr * 16 + lr);
#pragma unroll
        for (int mm2 = 0; mm2 < 2; ++mm2)
#pragma unroll
            for (int rr2 = 0; rr2 < 4; ++rr2) {
                i32x2 outv;
                outv[0] = (gq[mm2][rr2] & 0xFFFF)     | (gq[4 + mm2][rr2] << 16);  // gsel=0
                outv[1] = (gq[2 + mm2][rr2] & 0xFFFF) | (gq[6 + mm2][rr2] << 16);  // gsel=1
                int Lp = ((rr2 & 1) << 1) | (mm2 << 2) | ((rr2 >> 1) << 3) | (lg << 4);
                *(i32x2*)(ws + WS_GI + (size_t)tl * 524288u +
                          (size_t)((batch * 8u + (unsigned)wid) * 64u + (unsigned)Lp) * 4u) = outv;
            }
        __syncthreads();
    }
}

// ---------------- recurrence: 256 WGs x 1 batch row, W_hh resident in registers ----------
// lane bits: 0=gsel(G-half), 1=cp(plane/k bit0), 2=mm(k bit4), 3=X(k bit1), 4-5=sg(k bits2-3)
// k_own = w*32 + mm*16 + sg*4 + 2X + cp ; slots: G=gsel and G=gsel+2 at k_own
// h-plane LDS layout (bank-conflict-free): addr(p,k) = (k>>6)*128 + p*64 + ((k>>4)&3)*16 + (k&15)
__launch_bounds__(512, 2)
__global__ void recur_kernel(uint8_t* __restrict__ ws, float* __restrict__ out, int t0, int cs) {
    __shared__ __align__(16) uint8_t hbuf[2][512];    // [dbuf][interleaved planes]
    __shared__ long long redl[8];
    int tid = threadIdx.x, w = tid >> 6, lane = tid & 63;
    int wb = blockIdx.x;                              // batch row
    int gsel = lane & 1;
    int cp   = (lane >> 1) & 1;
    int mm   = (lane >> 2) & 1;
    int X    = (lane >> 3) & 1;
    int sg   = lane >> 4;
    uint8_t* hb0 = &hbuf[0][0];

    // W_hh fragments -> registers (persistent across all steps)
    i32x4 wf[8][4];
#pragma unroll
    for (int t8 = 0; t8 < 8; ++t8)
#pragma unroll
        for (int ks = 0; ks < 4; ++ks)
            wf[t8][ks] = *(const i32x4*)(ws + WS_WFRAG + (((unsigned)(w * 8 + t8) * 4 + ks) << 10) + lane * 16);

    // B-frag read addr: k = ks*64 + sg*16 + j, plane cp -> ks*128 + cp*64 + sg*16 (+j)
    // wave covers banks 0..31 exactly once per ks -> zero conflicts
    int addrB[4];
#pragma unroll
    for (int ks = 0; ks < 4; ++ks)
        addrB[ks] = ks * 128 + cp * 64 + sg * 16;

    int k_own = w * 32 + mm * 16 + sg * 4 + 2 * X + cp;
    // packed h write: one dword per (gsel, mm, sg) covering k = base..base+3
    int addrW4 = (w >> 1) * 128 + gsel * 64 + ((w & 1) * 2 + mm) * 16 + sg * 4;
    int biasP[2], wlv;
    {
        const int* bhh256 = (const int*)(ws + WS_BIASHH);
        int G0 = gsel, G1 = gsel + 2;
        biasP[0] = bhh256[G0 * 256 + k_own] + 768 * 256;                 // sigmoid pre-bias
        biasP[1] = bhh256[G1 * 256 + k_own] + (G1 == 2 ? 0 : 768 * 256); // G2 tanh: none
        wlv = ((const int*)(ws + WS_WLIN))[k_own];
    }
    size_t gioff = (size_t)((unsigned)wb * 8u + (unsigned)w) * 256u + (unsigned)lane * 4u;

    uint8_t* hst = ws + WS_HSTATE + (unsigned)wb * 512u;
    int* cst = (int*)(ws + WS_CSTATE) + (unsigned)wb * 512u + (unsigned)tid;

    int c_;
    if (t0 == 0) {
        c_ = 0;
        if (tid < 128) *(uint32_t*)(hb0 + tid * 4) = 0u;
    } else {
        c_ = *cst;
        if (tid < 128) *(uint32_t*)(hb0 + tid * 4) = *(const uint32_t*)(hst + tid * 4);
    }
    // prefetch gi for step 0 (stays in VGPRs across the barrier)
    int gcur = *(const int*)(ws + WS_GI + gioff);
    int gnx;
    __syncthreads();

    int hl_ = 0;
    const i32x4 zerov = {0, 0, 0, 0};

    // PLANEPAIR: u = acc[t8][2X], v = acc[t8][2X+1] with t8 = gsel?(mm?T3:T2):(mm?T1:T0)
#define PLANEPAIR(T0, T1, T2, T3, U, V)                                                \
    int U, V;                                                                          \
    {                                                                                  \
        int ua = X ? acc[T0][2] : acc[T0][0], va = X ? acc[T0][3] : acc[T0][1];        \
        int ub = X ? acc[T1][2] : acc[T1][0], vb = X ? acc[T1][3] : acc[T1][1];        \
        int uc = X ? acc[T2][2] : acc[T2][0], vc = X ? acc[T2][3] : acc[T2][1];        \
        int ud = X ? acc[T3][2] : acc[T3][0], vd = X ? acc[T3][3] : acc[T3][1];        \
        int u0 = mm ? ub : ua, v0 = mm ? vb : va;                                      \
        int u1 = mm ? ud : uc, v1 = mm ? vd : vc;                                      \
        U = gsel ? u1 : u0;                                                            \
        V = gsel ? v1 : v0;                                                            \
    }
    // SLOT: plane combine via partner lane^2 (DPP quad_perm, no DS); d = 4*a + b
#define SLOT(U, V, BIAS, OUTG)                                                         \
    int OUTG;                                                                          \
    {                                                                                  \
        int own = cp ? V : U;                                                          \
        int snd = cp ? U : V;                                                          \
        int z = DPPX2(snd);                                                            \
        int hi = cp ? z : own;                                                         \
        int lo = cp ? own : z;                                                         \
        OUTG = RHE8(hi * 4 + lo + (BIAS));                                             \
    }
#define STEP(PP, GUSE, GPRE, TPRE)                                                     \
    {                                                                                  \
        GPRE = *(const int*)(ws + WS_GI + (size_t)(TPRE) * 524288u + gioff);           \
        i32x4 acc[8];                                                                  \
        _Pragma("unroll")                                                              \
        for (int ks = 0; ks < 4; ++ks) {                                               \
            i32x4 bf = *(const i32x4*)(hb0 + (PP) * 512 + addrB[ks]);                  \
            _Pragma("unroll")                                                          \
            for (int t8 = 0; t8 < 8; ++t8)                                             \
                acc[t8] = (ks == 0) ? MFMA_I8(wf[t8][0], bf, zerov)                    \
                                    : MFMA_I8(wf[t8][ks], bf, acc[t8]);                \
        }                                                                              \
        PLANEPAIR(0, 1, 2, 3, uA, vA)                                                  \
        PLANEPAIR(4, 5, 6, 7, uB, vB)                                                  \
        SLOT(uA, vA, biasP[0], gA)                                                     \
        SLOT(uB, vB, biasP[1], gB)                                                     \
        int givlo = ((GUSE) << 16) >> 16, givhi = (GUSE) >> 16;                        \
        int first = sigq(iclamp(gA + givlo, 0, 1536));        /* gsel0: i, gsel1: f */ \
        int sigB  = sigq(iclamp(gB + givhi, 0, 1536));                                 \
        int clpB  = iclamp(gB + givhi, -256, 256);            /* tanh path */          \
        int second = gsel ? sigB : clpB;                      /* gsel0: c, gsel1: o */ \
        int z1 = DPPX1(first);                                                         \
        int z2 = DPPX1(second);                                                        \
        int i_g = gsel ? z1 : first;                                                   \
        int f_g = gsel ? first : z1;                                                   \
        int c_g = gsel ? z2 : second;                                                  \
        int o_g = gsel ? second : z2;                                                  \
        int fcq = RHE8(__mul24(f_g, c_));                                              \
        int icq = RHE8(__mul24(i_g, c_g));                                             \
        int cn  = iclamp(fcq + icq, -32768, 32767);                                    \
        c_ = cn;                                                                       \
        int th = iclamp(cn, -256, 256);                                                \
        int hq = RHE8(__mul24(o_g, th));                                               \
        /* packed dword write: gather 4 plane-bytes (k offsets 2X+cp) via DPP */       \
        unsigned hby = (unsigned)(gsel ? (hq & 3) : (hq >> 2)) & 255u;                 \
        unsigned pv = hby << (8 * (2 * X + cp));                                       \
        pv |= (unsigned)DPPX2((int)pv);                                                \
        pv |= (unsigned)DPPROR8((int)pv);                                              \
        if ((lane & 10) == 0)                                                          \
            *(uint32_t*)(hb0 + ((PP) ^ 1) * 512 + addrW4) = pv;                        \
        hl_ = hq;                                                                      \
        BAR();                                                                         \
    }

    for (int tl = 0; tl < cs; tl += 2) {
        int tn2 = (tl + 2 < cs) ? tl + 2 : 0;   // harmless wrap on last iter
        STEP(0, gcur, gnx, tl + 1)
        STEP(1, gnx, gcur, tn2)
    }
#undef STEP
#undef SLOT
#undef PLANEPAIR

    // save state for next chunk (final buffer parity is 0 since cs is even)
    if (tid < 128) *(uint32_t*)(hst + tid * 4) = *(const uint32_t*)(hb0 + tid * 4);
    *cst = c_;

    if (t0 + cs == 512) {   // head: out = quant(h_last @ w_lin^T + b_lin), exact int64
        long long s = gsel ? 0LL : (long long)hl_ * (long long)wlv;
        s += __shfl_xor(s, 1);
        s += __shfl_xor(s, 2);
        s += __shfl_xor(s, 4);
        s += __shfl_xor(s, 8);
        s += __shfl_xor(s, 16);
        s += __shfl_xor(s, 32);
        if (lane == 0) redl[w] = s;
        __syncthreads();
        if (tid == 0) {
            long long tot = 0;
#pragma unroll
            for (int ww = 0; ww < 8; ++ww) tot += redl[ww];
            tot += 256LL * (long long)((const int*)(ws + WS_BLIN))[0];
            long long q = ((tot + 127) + ((tot >> 8) & 1)) >> 8;
            q = q < -32768 ? -32768 : (q > 32767 ? 32767 : q);
            out[wb] = (float)q * 0.00390625f;
        }
    }
}

// ---------------- host ----------------
extern "C" void kernel_launch(void* const* d_in, const int* in_sizes, int n_in,
                              void* d_out, int out_size, void* d_ws, size_t ws_size,
                              hipStream_t stream) {
    const float* x    = (const float*)d_in[0];
    const float* wih  = (const float*)d_in[1];
    const float* whh  = (const float*)d_in[2];
    const float* bih  = (const float*)d_in[3];
    const float* bhh  = (const float*)d_in[4];
    const float* wlin = (const float*)d_in[5];
    const float* blin = (const float*)d_in[6];
    float* out = (float*)d_out;
    uint8_t* ws = (uint8_t*)d_ws;

    prep_kernel<<<512, 512, 0, stream>>>(wih, whh, bih, bhh, wlin, blin, ws);

    int cs = 512;
    while ((size_t)WS_GI + (size_t)cs * 524288u > ws_size && cs > 8) cs >>= 1;

    for (int t0 = 0; t0 < 512; t0 += cs) {
        gi_kernel<<<dim3(16, cs / 4), 512, 0, stream>>>(x, ws, t0);
        recur_kernel<<<256, 512, 0, stream>>>(ws, out, t0, cs);
    }
}

// Round 9
// 519.635 us; speedup vs baseline: 1.2291x; 1.0180x over previous
//
#include <hip/hip_runtime.h>
#include <stdint.h>
#include <stddef.h>

typedef int i32x4 __attribute__((ext_vector_type(4)));
typedef int i32x2 __attribute__((ext_vector_type(2)));

// ---------------- workspace layout (bytes) ----------------
#define WS_WFRAG   0u          // 262144  w_hh int8, [w8][t8][ks4][lane64][16]
#define WS_WIH     262144u     // 131072  w_ih int8 [1024][128]
#define WS_BIASHH  393216u     // 4096    b_hh_int*256 as i32 [1024]
#define WS_BIASIH  397312u     // 4096    b_ih_int*256 as i32 [1024]
#define WS_WLIN    401408u     // 1024    w_lin int i32 [256]
#define WS_BLIN    402432u     // 4       b_lin int
#define WS_HSTATE  409600u     // 256 wg * 512 = 131072 (h planes)
#define WS_CSTATE  540672u     // 256*512*4 = 524288 (c per lane)
#define WS_GI      1064960u    // cs * 524288 bytes (chunk-local step ring)

#define MFMA_I8(a,b,c) __builtin_amdgcn_mfma_i32_16x16x64_i8(a,b,c,0,0,0)
#define RHE8(x) ((((x) + 127) + (((x) >> 8) & 1)) >> 8)

// cross-lane exchanges on the VALU pipe (no DS unit)
#define DPPX1(v)   __builtin_amdgcn_update_dpp(0, (v), 0xB1, 0xF, 0xF, true)   // quad [1,0,3,2] = lane^1
#define DPPX2(v)   __builtin_amdgcn_update_dpp(0, (v), 0x4E, 0xF, 0xF, true)   // quad [2,3,0,1] = lane^2
#define DPPROR8(v) __builtin_amdgcn_update_dpp(0, (v), 0x128, 0xF, 0xF, true)  // row_ror:8 = lane^8

// LDS-drain-only barrier: keeps global prefetch loads in flight across steps.
#define BAR() do { asm volatile("s_waitcnt lgkmcnt(0)" ::: "memory"); \
                   __builtin_amdgcn_s_barrier(); } while (0)

__device__ __forceinline__ float clamp3(float x, float lo, float hi) {
    return __builtin_amdgcn_fmed3f(x, lo, hi);
}
__device__ __forceinline__ float q16f(float x) {
    return clamp3(__builtin_rintf(x * 256.0f), -32768.0f, 32767.0f);
}
__device__ __forceinline__ int iclamp(int v, int lo, int hi) {
    return v < lo ? lo : (v > hi ? hi : v);
}
// exact round-half-even of u/6 for u in [0,1536] (== np's fp64 quant(hard_sigmoid) path)
__device__ __forceinline__ int sigq(int u) {
    int q = __mul24(u, 43691) >> 18;       // exact floor(u/6) for u <= 1536
    int r = u - __mul24(q, 6);
    return q + (((r + (q & 1)) > 3) ? 1 : 0);
}

// ---------------- prep: quantize weights into fragment layouts ----------------
__global__ void prep_kernel(const float* __restrict__ wih, const float* __restrict__ whh,
                            const float* __restrict__ bih, const float* __restrict__ bhh,
                            const float* __restrict__ wlin, const float* __restrict__ blin,
                            uint8_t* __restrict__ ws) {
    int tid = blockIdx.x * blockDim.x + threadIdx.x;   // 262144 threads
    {   // w_hh -> A-fragment order: [w][t8][ks][lane][16B]
        int p = tid;
        int j = p & 15, lane = (p >> 4) & 63, ks = (p >> 10) & 3, t8 = (p >> 12) & 7, w = (p >> 15) & 7;
        int row = (t8 >> 1) * 256 + w * 32 + (t8 & 1) * 16 + (lane & 15);
        int k = ks * 64 + (lane >> 4) * 16 + j;
        int v = (int)q16f(whh[row * 256 + k]);
        v = iclamp(v, -127, 127);
        ((int8_t*)(ws + WS_WFRAG))[p] = (int8_t)v;
    }
    if (tid < 131072) {  // w_ih plain [gcol][k] int8
        int gcol = tid >> 7, k = tid & 127;
        int v = (int)q16f(wih[gcol * 128 + k]);
        v = iclamp(v, -127, 127);
        ((int8_t*)(ws + WS_WIH))[tid] = (int8_t)v;
    }
    if (tid < 1024) {    // biases scaled to 2^-16 units (i32)
        ((int*)(ws + WS_BIASHH))[tid] = ((int)q16f(bhh[tid])) * 256;
        ((int*)(ws + WS_BIASIH))[tid] = ((int)q16f(bih[tid])) * 256;
    }
    if (tid < 256) ((int*)(ws + WS_WLIN))[tid] = (int)q16f(wlin[tid]);
    if (tid == 0)  ((int*)(ws + WS_BLIN))[0]   = (int)q16f(blin[0]);
}

// ---------------- gi = quant(xq @ w_ih_q^T + b_ih_q), 4 steps per block ----------
__launch_bounds__(512, 2)
__global__ void gi_kernel(const float* __restrict__ x, uint8_t* __restrict__ ws, int t0) {
    __shared__ uint8_t xa[2][2048], xb[2][2048];   // x hi/lo i8 planes, double-buffered
    int tid = threadIdx.x;
    int wgr = blockIdx.x;              // batch group of 16, 0..15
    int tlb = blockIdx.y * 4;          // first of 4 chunk-local steps
    int wid = tid >> 6, lane = tid & 63, lr = lane & 15, lg = lane >> 4;

    // w_ih A-fragments + bias (loaded once, reused for 4 steps)
    const uint8_t* wq = ws + WS_WIH;
    i32x4 af[8][2];
#pragma unroll
    for (int mt = 0; mt < 8; ++mt) {
        int gcol = (mt >> 1) * 256 + wid * 32 + (mt & 1) * 16 + lr;
#pragma unroll
        for (int kt = 0; kt < 2; ++kt)
            af[mt][kt] = *(const i32x4*)(wq + gcol * 128 + kt * 64 + lg * 16);
    }
    i32x4 bcv[8];
    const int* bi = (const int*)(ws + WS_BIASIH);
#pragma unroll
    for (int mt = 0; mt < 8; ++mt) {
        int gb = (mt >> 1) * 256 + wid * 32 + (mt & 1) * 16 + lg * 4;
        bcv[mt] = *(const i32x4*)(bi + gb);
    }

    auto STAGE = [&](int tl, int buf) {
        int row = tid >> 5, c4 = (tid & 31) * 4;
        int b = wgr * 16 + row;
        const float4 xv = *(const float4*)(x + ((size_t)b * 512 + (t0 + tl)) * 128 + c4);
        int v0 = (int)q16f(xv.x), v1 = (int)q16f(xv.y), v2 = (int)q16f(xv.z), v3 = (int)q16f(xv.w);
        uint32_t da = ((uint32_t)((v0 >> 7) & 255)) | ((uint32_t)((v1 >> 7) & 255) << 8) |
                      ((uint32_t)((v2 >> 7) & 255) << 16) | ((uint32_t)((v3 >> 7) & 255) << 24);
        uint32_t db = ((uint32_t)(v0 & 127)) | ((uint32_t)(v1 & 127) << 8) |
                      ((uint32_t)(v2 & 127) << 16) | ((uint32_t)(v3 & 127) << 24);
        int addr = row * 128 + (((c4 >> 4) ^ (row & 7)) * 16) + (c4 & 15);
        *(uint32_t*)(&xa[buf][0] + addr) = da;
        *(uint32_t*)(&xb[buf][0] + addr) = db;
    };

    STAGE(tlb, 0);
    __syncthreads();

    for (int s4 = 0; s4 < 4; ++s4) {
        int tl = tlb + s4;
        if (s4 < 3) STAGE(tl + 1, (s4 + 1) & 1);
        int buf = s4 & 1;

        i32x4 bha[2], bhb[2];
#pragma unroll
        for (int kt = 0; kt < 2; ++kt) {
            int addr = lr * 128 + ((((kt * 4) + lg) ^ (lr & 7)) * 16);
            bha[kt] = *(const i32x4*)(&xa[buf][0] + addr);
            bhb[kt] = *(const i32x4*)(&xb[buf][0] + addr);
        }
        i32x4 acch[8], accl[8];
#pragma unroll
        for (int mt = 0; mt < 8; ++mt) {
            i32x4 z = {0, 0, 0, 0};
            acch[mt] = MFMA_I8(af[mt][0], bha[0], z);
            accl[mt] = MFMA_I8(af[mt][0], bhb[0], bcv[mt]);   // bias folded into C
            acch[mt] = MFMA_I8(af[mt][1], bha[1], acch[mt]);
            accl[mt] = MFMA_I8(af[mt][1], bhb[1], accl[mt]);
        }
        int gq[8][4];
#pragma unroll
        for (int mt = 0; mt < 8; ++mt)
#pragma unroll
            for (int rr = 0; rr < 4; ++rr) {
                int v = acch[mt][rr] * 128 + accl[mt][rr];
                gq[mt][rr] = iclamp(RHE8(v), -32768, 32767);
            }
        // scatter to recur slot order: WG = batch; lane bits gsel|cp<<1|mm<<2|X<<3|sg<<4
        unsigned batch = (unsigned)(wgr * 16 + lr);
#pragma unroll
        for (int mm2 = 0; mm2 < 2; ++mm2)
#pragma unroll
            for (int rr2 = 0; rr2 < 4; ++rr2) {
                i32x2 outv;
                outv[0] = (gq[mm2][rr2] & 0xFFFF)     | (gq[4 + mm2][rr2] << 16);  // gsel=0
                outv[1] = (gq[2 + mm2][rr2] & 0xFFFF) | (gq[6 + mm2][rr2] << 16);  // gsel=1
                int Lp = ((rr2 & 1) << 1) | (mm2 << 2) | ((rr2 >> 1) << 3) | (lg << 4);
                *(i32x2*)(ws + WS_GI + (size_t)tl * 524288u +
                          (size_t)((batch * 8u + (unsigned)wid) * 64u + (unsigned)Lp) * 4u) = outv;
            }
        __syncthreads();
    }
}

// ---------------- recurrence: 256 WGs x 1 batch row, W_hh resident in registers ----------
// lane bits: 0=gsel(G-half), 1=cp(plane/k bit0), 2=mm(k bit4), 3=X(k bit1), 4-5=sg(k bits2-3)
// k_own = w*32 + mm*16 + sg*4 + 2X + cp ; slots: G=gsel and G=gsel+2 at k_own
// h-plane LDS layout (bank-conflict-free): addr(p,k) = (k>>6)*128 + p*64 + ((k>>4)&3)*16 + (k&15)
__launch_bounds__(512, 2)
__global__ void recur_kernel(uint8_t* __restrict__ ws, float* __restrict__ out, int t0, int cs) {
    __shared__ __align__(16) uint8_t hbuf[2][512];    // [dbuf][interleaved planes]
    __shared__ long long redl[8];
    int tid = threadIdx.x, w = tid >> 6, lane = tid & 63;
    int wb = blockIdx.x;                              // batch row
    int gsel = lane & 1;
    int cp   = (lane >> 1) & 1;
    int mm   = (lane >> 2) & 1;
    int X    = (lane >> 3) & 1;
    int sg   = lane >> 4;
    uint8_t* hb0 = &hbuf[0][0];

    // W_hh fragments -> registers (persistent across all steps)
    i32x4 wf[8][4];
#pragma unroll
    for (int t8 = 0; t8 < 8; ++t8)
#pragma unroll
        for (int ks = 0; ks < 4; ++ks)
            wf[t8][ks] = *(const i32x4*)(ws + WS_WFRAG + (((unsigned)(w * 8 + t8) * 4 + ks) << 10) + lane * 16);

    // B-frag read addr: wave covers banks 0..31 exactly once per ks -> zero conflicts
    int addrB[4];
#pragma unroll
    for (int ks = 0; ks < 4; ++ks)
        addrB[ks] = ks * 128 + cp * 64 + sg * 16;

    int k_own = w * 32 + mm * 16 + sg * 4 + 2 * X + cp;
    // packed h write: one dword per (gsel, mm, sg) covering k = base..base+3
    int addrW4 = (w >> 1) * 128 + gsel * 64 + ((w & 1) * 2 + mm) * 16 + sg * 4;
    int hsh = 8 * (2 * X + cp);                       // byte position in packed dword
    int biasP[2], wlv;
    {
        const int* bhh256 = (const int*)(ws + WS_BIASHH);
        int G0 = gsel, G1 = gsel + 2;
        biasP[0] = bhh256[G0 * 256 + k_own] + 768 * 256;                 // sigmoid pre-bias
        biasP[1] = bhh256[G1 * 256 + k_own] + (G1 == 2 ? 0 : 768 * 256); // G2 tanh: none
        wlv = ((const int*)(ws + WS_WLIN))[k_own];
    }
    size_t gioff = (size_t)((unsigned)wb * 8u + (unsigned)w) * 256u + (unsigned)lane * 4u;

    uint8_t* hst = ws + WS_HSTATE + (unsigned)wb * 512u;
    int* cst = (int*)(ws + WS_CSTATE) + (unsigned)wb * 512u + (unsigned)tid;

    int c_;
    if (t0 == 0) {
        c_ = 0;
        if (tid < 128) *(uint32_t*)(hb0 + tid * 4) = 0u;
    } else {
        c_ = *cst;
        if (tid < 128) *(uint32_t*)(hb0 + tid * 4) = *(const uint32_t*)(hst + tid * 4);
    }
    // prefetch gi for step 0 (stays in VGPRs across the barrier)
    int gcur = *(const int*)(ws + WS_GI + gioff);
    int gnx;
    __syncthreads();

    int hl_ = 0;
    const i32x4 zerov = {0, 0, 0, 0};

    // PLANEPAIR: u = acc[t8][2X], v = acc[t8][2X+1] with t8 = gsel?(mm?T3:T2):(mm?T1:T0)
#define PLANEPAIR(T0, T1, T2, T3, U, V)                                                \
    int U, V;                                                                          \
    {                                                                                  \
        int ua = X ? acc[T0][2] : acc[T0][0], va = X ? acc[T0][3] : acc[T0][1];        \
        int ub = X ? acc[T1][2] : acc[T1][0], vb = X ? acc[T1][3] : acc[T1][1];        \
        int uc = X ? acc[T2][2] : acc[T2][0], vc = X ? acc[T2][3] : acc[T2][1];        \
        int ud = X ? acc[T3][2] : acc[T3][0], vd = X ? acc[T3][3] : acc[T3][1];        \
        int u0 = mm ? ub : ua, v0 = mm ? vb : va;                                      \
        int u1 = mm ? ud : uc, v1 = mm ? vd : vc;                                      \
        U = gsel ? u1 : u0;                                                            \
        V = gsel ? v1 : v0;                                                            \
    }
    // SLOT: plane combine via partner lane^2 (DPP quad_perm, no DS); d = 4*a + b
#define SLOT(U, V, BIAS, OUTG)                                                         \
    int OUTG;                                                                          \
    {                                                                                  \
        int own = cp ? V : U;                                                          \
        int snd = cp ? U : V;                                                          \
        int z = DPPX2(snd);                                                            \
        int hi = cp ? z : own;                                                         \
        int lo = cp ? own : z;                                                         \
        OUTG = RHE8(hi * 4 + lo + (BIAS));                                             \
    }
    // Gate tail (local-product form): lane gsel=0 computes icq = RHE8(i*c_g) locally
    // (first=i, second=c_g in-lane); lane gsel=1 computes fcq = RHE8(f*c_) locally
    // (first=f; c_ duplicated across the pair). One DPPX1 exchanges the products.
    // hq = RHE8(o*th) computed in gsel=1 lane, DPPX1-broadcast to gsel=0.
#define STEP(PP, GUSE, GPRE, TPRE)                                                     \
    {                                                                                  \
        GPRE = *(const int*)(ws + WS_GI + (size_t)(TPRE) * 524288u + gioff);           \
        __builtin_amdgcn_s_setprio(1);                                                 \
        i32x4 acc[8];                                                                  \
        _Pragma("unroll")                                                              \
        for (int ks = 0; ks < 4; ++ks) {                                               \
            i32x4 bf = *(const i32x4*)(hb0 + (PP) * 512 + addrB[ks]);                  \
            _Pragma("unroll")                                                          \
            for (int t8 = 0; t8 < 8; ++t8)                                             \
                acc[t8] = (ks == 0) ? MFMA_I8(wf[t8][0], bf, zerov)                    \
                                    : MFMA_I8(wf[t8][ks], bf, acc[t8]);                \
        }                                                                              \
        __builtin_amdgcn_s_setprio(0);                                                 \
        PLANEPAIR(0, 1, 2, 3, uA, vA)                                                  \
        PLANEPAIR(4, 5, 6, 7, uB, vB)                                                  \
        SLOT(uA, vA, biasP[0], gA)                                                     \
        SLOT(uB, vB, biasP[1], gB)                                                     \
        int givlo = ((GUSE) << 16) >> 16, givhi = (GUSE) >> 16;                        \
        int first = sigq(iclamp(gA + givlo, 0, 1536));        /* gsel0: i, gsel1: f */ \
        int gBs = gB + givhi;                                                          \
        int sigB = sigq(iclamp(gBs, 0, 1536));                                         \
        int clpB = iclamp(gBs, -256, 256);                                             \
        int second = gsel ? sigB : clpB;                      /* gsel0: c_g, gsel1: o */ \
        int marg = gsel ? c_ : second;                                                 \
        int ownp = RHE8(__mul24(first, marg));                /* gsel0: icq, gsel1: fcq */ \
        int othp = DPPX1(ownp);                                                        \
        int cn  = iclamp(ownp + othp, -32768, 32767);                                  \
        c_ = cn;                                                                       \
        int th = iclamp(cn, -256, 256);                                                \
        int hq1 = RHE8(__mul24(second, th));                  /* valid in gsel=1 */    \
        int hqp = DPPX1(hq1);                                                          \
        int hq = gsel ? hq1 : hqp;                                                     \
        /* packed dword write: gather 4 plane-bytes (k offsets 2X+cp) via DPP */       \
        unsigned hby = (unsigned)(gsel ? (hq & 3) : (hq >> 2)) & 255u;                 \
        unsigned pv = hby << hsh;                                                      \
        pv |= (unsigned)DPPX2((int)pv);                                                \
        pv |= (unsigned)DPPROR8((int)pv);                                              \
        if ((lane & 10) == 0)                                                          \
            *(uint32_t*)(hb0 + ((PP) ^ 1) * 512 + addrW4) = pv;                        \
        hl_ = hq;                                                                      \
        BAR();                                                                         \
    }

    for (int tl = 0; tl < cs; tl += 2) {
        int tn2 = (tl + 2 < cs) ? tl + 2 : 0;   // harmless wrap on last iter
        STEP(0, gcur, gnx, tl + 1)
        STEP(1, gnx, gcur, tn2)
    }
#undef STEP
#undef SLOT
#undef PLANEPAIR

    // save state for next chunk (final buffer parity is 0 since cs is even)
    if (tid < 128) *(uint32_t*)(hst + tid * 4) = *(const uint32_t*)(hb0 + tid * 4);
    *cst = c_;

    if (t0 + cs == 512) {   // head: out = quant(h_last @ w_lin^T + b_lin), exact int64
        long long s = gsel ? 0LL : (long long)hl_ * (long long)wlv;
        s += __shfl_xor(s, 1);
        s += __shfl_xor(s, 2);
        s += __shfl_xor(s, 4);
        s += __shfl_xor(s, 8);
        s += __shfl_xor(s, 16);
        s += __shfl_xor(s, 32);
        if (lane == 0) redl[w] = s;
        __syncthreads();
        if (tid == 0) {
            long long tot = 0;
#pragma unroll
            for (int ww = 0; ww < 8; ++ww) tot += redl[ww];
            tot += 256LL * (long long)((const int*)(ws + WS_BLIN))[0];
            long long q = ((tot + 127) + ((tot >> 8) & 1)) >> 8;
            q = q < -32768 ? -32768 : (q > 32767 ? 32767 : q);
            out[wb] = (float)q * 0.00390625f;
        }
    }
}

// ---------------- host ----------------
extern "C" void kernel_launch(void* const* d_in, const int* in_sizes, int n_in,
                              void* d_out, int out_size, void* d_ws, size_t ws_size,
                              hipStream_t stream) {
    const float* x    = (const float*)d_in[0];
    const float* wih  = (const float*)d_in[1];
    const float* whh  = (const float*)d_in[2];
    const float* bih  = (const float*)d_in[3];
    const float* bhh  = (const float*)d_in[4];
    const float* wlin = (const float*)d_in[5];
    const float* blin = (const float*)d_in[6];
    float* out = (float*)d_out;
    uint8_t* ws = (uint8_t*)d_ws;

    prep_kernel<<<512, 512, 0, stream>>>(wih, whh, bih, bhh, wlin, blin, ws);

    int cs = 512;
    while ((size_t)WS_GI + (size_t)cs * 524288u > ws_size && cs > 8) cs >>= 1;

    for (int t0 = 0; t0 < 512; t0 += cs) {
        gi_kernel<<<dim3(16, cs / 4), 512, 0, stream>>>(x, ws, t0);
        recur_kernel<<<256, 512, 0, stream>>>(ws, out, t0, cs);
    }
}

// Round 10
// 516.742 us; speedup vs baseline: 1.2359x; 1.0056x over previous
//
#include <hip/hip_runtime.h>
#include <stdint.h>
#include <stddef.h>

typedef int i32x4 __attribute__((ext_vector_type(4)));
typedef int i32x2 __attribute__((ext_vector_type(2)));

// ---------------- workspace layout (bytes) ----------------
#define WS_WFRAG   0u          // 262144  w_hh int8, [w8][t8][ks4][lane64][16]
#define WS_WIH     262144u     // 131072  w_ih int8 [1024][128]
#define WS_BIASHH  393216u     // 4096    b_hh_int*256 as i32 [1024]
#define WS_BIASIH  397312u     // 4096    b_ih_int*256 as i32 [1024]
#define WS_WLIN    401408u     // 1024    w_lin int i32 [256]
#define WS_BLIN    402432u     // 4       b_lin int
#define WS_HSTATE  409600u     // 256 wg * 512 = 131072 (h planes)
#define WS_CSTATE  540672u     // 256*512*4 = 524288 (c per lane)
#define WS_GI      1064960u    // cs * 524288 bytes (chunk-local step ring)

#define MFMA_I8(a,b,c) __builtin_amdgcn_mfma_i32_16x16x64_i8(a,b,c,0,0,0)
#define RHE8(x) ((((x) + 127) + (((x) >> 8) & 1)) >> 8)

// cross-lane exchanges on the VALU pipe (no DS unit)
#define DPPX1(v)   __builtin_amdgcn_update_dpp(0, (v), 0xB1, 0xF, 0xF, true)   // quad [1,0,3,2] = lane^1
#define DPPX2(v)   __builtin_amdgcn_update_dpp(0, (v), 0x4E, 0xF, 0xF, true)   // quad [2,3,0,1] = lane^2
#define DPPROR8(v) __builtin_amdgcn_update_dpp(0, (v), 0x128, 0xF, 0xF, true)  // row_ror:8 = lane^8

// LDS-drain-only barrier: keeps global prefetch loads in flight across steps.
#define BAR() do { asm volatile("s_waitcnt lgkmcnt(0)" ::: "memory"); \
                   __builtin_amdgcn_s_barrier(); } while (0)

__device__ __forceinline__ float clamp3(float x, float lo, float hi) {
    return __builtin_amdgcn_fmed3f(x, lo, hi);
}
__device__ __forceinline__ float q16f(float x) {
    return clamp3(__builtin_rintf(x * 256.0f), -32768.0f, 32767.0f);
}
__device__ __forceinline__ int iclamp(int v, int lo, int hi) {
    return v < lo ? lo : (v > hi ? hi : v);
}
// exact round-half-even of u/6 for u in [0,1536] (== np's fp64 quant(hard_sigmoid) path)
__device__ __forceinline__ int sigq(int u) {
    int q = __mul24(u, 43691) >> 18;       // exact floor(u/6) for u <= 1536
    int r = u - __mul24(q, 6);
    return q + (((r + (q & 1)) > 3) ? 1 : 0);
}

// ---------------- prep: quantize weights into fragment layouts ----------------
__global__ void prep_kernel(const float* __restrict__ wih, const float* __restrict__ whh,
                            const float* __restrict__ bih, const float* __restrict__ bhh,
                            const float* __restrict__ wlin, const float* __restrict__ blin,
                            uint8_t* __restrict__ ws) {
    int tid = blockIdx.x * blockDim.x + threadIdx.x;   // 262144 threads
    {   // w_hh -> A-fragment order: [w][t8][ks][lane][16B]
        int p = tid;
        int j = p & 15, lane = (p >> 4) & 63, ks = (p >> 10) & 3, t8 = (p >> 12) & 7, w = (p >> 15) & 7;
        int row = (t8 >> 1) * 256 + w * 32 + (t8 & 1) * 16 + (lane & 15);
        int k = ks * 64 + (lane >> 4) * 16 + j;
        int v = (int)q16f(whh[row * 256 + k]);
        v = iclamp(v, -127, 127);
        ((int8_t*)(ws + WS_WFRAG))[p] = (int8_t)v;
    }
    if (tid < 131072) {  // w_ih plain [gcol][k] int8
        int gcol = tid >> 7, k = tid & 127;
        int v = (int)q16f(wih[gcol * 128 + k]);
        v = iclamp(v, -127, 127);
        ((int8_t*)(ws + WS_WIH))[tid] = (int8_t)v;
    }
    if (tid < 1024) {    // biases scaled to 2^-16 units (i32)
        ((int*)(ws + WS_BIASHH))[tid] = ((int)q16f(bhh[tid])) * 256;
        ((int*)(ws + WS_BIASIH))[tid] = ((int)q16f(bih[tid])) * 256;
    }
    if (tid < 256) ((int*)(ws + WS_WLIN))[tid] = (int)q16f(wlin[tid]);
    if (tid == 0)  ((int*)(ws + WS_BLIN))[0]   = (int)q16f(blin[0]);
}

// ---------------- gi = quant(xq @ w_ih_q^T + b_ih_q), 4 steps per block ----------
__launch_bounds__(512, 2)
__global__ void gi_kernel(const float* __restrict__ x, uint8_t* __restrict__ ws, int t0) {
    __shared__ uint8_t xa[2][2048], xb[2][2048];   // x hi/lo i8 planes, double-buffered
    int tid = threadIdx.x;
    int wgr = blockIdx.x;              // batch group of 16, 0..15
    int tlb = blockIdx.y * 4;          // first of 4 chunk-local steps
    int wid = tid >> 6, lane = tid & 63, lr = lane & 15, lg = lane >> 4;

    // w_ih A-fragments + bias (loaded once, reused for 4 steps)
    const uint8_t* wq = ws + WS_WIH;
    i32x4 af[8][2];
#pragma unroll
    for (int mt = 0; mt < 8; ++mt) {
        int gcol = (mt >> 1) * 256 + wid * 32 + (mt & 1) * 16 + lr;
#pragma unroll
        for (int kt = 0; kt < 2; ++kt)
            af[mt][kt] = *(const i32x4*)(wq + gcol * 128 + kt * 64 + lg * 16);
    }
    i32x4 bcv[8];
    const int* bi = (const int*)(ws + WS_BIASIH);
#pragma unroll
    for (int mt = 0; mt < 8; ++mt) {
        int gb = (mt >> 1) * 256 + wid * 32 + (mt & 1) * 16 + lg * 4;
        bcv[mt] = *(const i32x4*)(bi + gb);
    }

    auto STAGE = [&](int tl, int buf) {
        int row = tid >> 5, c4 = (tid & 31) * 4;
        int b = wgr * 16 + row;
        const float4 xv = *(const float4*)(x + ((size_t)b * 512 + (t0 + tl)) * 128 + c4);
        int v0 = (int)q16f(xv.x), v1 = (int)q16f(xv.y), v2 = (int)q16f(xv.z), v3 = (int)q16f(xv.w);
        uint32_t da = ((uint32_t)((v0 >> 7) & 255)) | ((uint32_t)((v1 >> 7) & 255) << 8) |
                      ((uint32_t)((v2 >> 7) & 255) << 16) | ((uint32_t)((v3 >> 7) & 255) << 24);
        uint32_t db = ((uint32_t)(v0 & 127)) | ((uint32_t)(v1 & 127) << 8) |
                      ((uint32_t)(v2 & 127) << 16) | ((uint32_t)(v3 & 127) << 24);
        int addr = row * 128 + (((c4 >> 4) ^ (row & 7)) * 16) + (c4 & 15);
        *(uint32_t*)(&xa[buf][0] + addr) = da;
        *(uint32_t*)(&xb[buf][0] + addr) = db;
    };

    STAGE(tlb, 0);
    __syncthreads();

    for (int s4 = 0; s4 < 4; ++s4) {
        int tl = tlb + s4;
        if (s4 < 3) STAGE(tl + 1, (s4 + 1) & 1);
        int buf = s4 & 1;

        i32x4 bha[2], bhb[2];
#pragma unroll
        for (int kt = 0; kt < 2; ++kt) {
            int addr = lr * 128 + ((((kt * 4) + lg) ^ (lr & 7)) * 16);
            bha[kt] = *(const i32x4*)(&xa[buf][0] + addr);
            bhb[kt] = *(const i32x4*)(&xb[buf][0] + addr);
        }
        i32x4 acch[8], accl[8];
#pragma unroll
        for (int mt = 0; mt < 8; ++mt) {
            i32x4 z = {0, 0, 0, 0};
            acch[mt] = MFMA_I8(af[mt][0], bha[0], z);
            accl[mt] = MFMA_I8(af[mt][0], bhb[0], bcv[mt]);   // bias folded into C
            acch[mt] = MFMA_I8(af[mt][1], bha[1], acch[mt]);
            accl[mt] = MFMA_I8(af[mt][1], bhb[1], accl[mt]);
        }
        int gq[8][4];
#pragma unroll
        for (int mt = 0; mt < 8; ++mt)
#pragma unroll
            for (int rr = 0; rr < 4; ++rr) {
                int v = acch[mt][rr] * 128 + accl[mt][rr];
                gq[mt][rr] = iclamp(RHE8(v), -32768, 32767);
            }
        // scatter to recur slot order: WG = batch; lane bits gsel|cp<<1|mm<<2|X<<3|sg<<4
        unsigned batch = (unsigned)(wgr * 16 + lr);
#pragma unroll
        for (int mm2 = 0; mm2 < 2; ++mm2)
#pragma unroll
            for (int rr2 = 0; rr2 < 4; ++rr2) {
                i32x2 outv;
                outv[0] = (gq[mm2][rr2] & 0xFFFF)     | (gq[4 + mm2][rr2] << 16);  // gsel=0
                outv[1] = (gq[2 + mm2][rr2] & 0xFFFF) | (gq[6 + mm2][rr2] << 16);  // gsel=1
                int Lp = ((rr2 & 1) << 1) | (mm2 << 2) | ((rr2 >> 1) << 3) | (lg << 4);
                *(i32x2*)(ws + WS_GI + (size_t)tl * 524288u +
                          (size_t)((batch * 8u + (unsigned)wid) * 64u + (unsigned)Lp) * 4u) = outv;
            }
        __syncthreads();
    }
}

// ---------------- recurrence: 256 WGs x 1 batch row, W_hh resident in registers ----------
// lane bits: 0=gsel(G-half), 1=cp(plane/k bit0), 2=mm(k bit4), 3=X(k bit1), 4-5=sg(k bits2-3)
// k_own = w*32 + mm*16 + sg*4 + 2X + cp ; slots: G=gsel and G=gsel+2 at k_own
// h-plane LDS layout (bank-conflict-free): addr(p,k) = (k>>6)*128 + p*64 + ((k>>4)&3)*16 + (k&15)
__launch_bounds__(512, 2)
__global__ void recur_kernel(uint8_t* __restrict__ ws, float* __restrict__ out, int t0, int cs) {
    __shared__ __align__(16) uint8_t hbuf[2][512];    // [dbuf][interleaved planes]
    __shared__ long long redl[8];
    int tid = threadIdx.x, w = tid >> 6, lane = tid & 63;
    int wb = blockIdx.x;                              // batch row
    int gsel = lane & 1;
    int cp   = (lane >> 1) & 1;
    int mm   = (lane >> 2) & 1;
    int X    = (lane >> 3) & 1;
    int sg   = lane >> 4;
    uint8_t* hb0 = &hbuf[0][0];

    // W_hh fragments -> registers (persistent across all steps)
    i32x4 wf[8][4];
#pragma unroll
    for (int t8 = 0; t8 < 8; ++t8)
#pragma unroll
        for (int ks = 0; ks < 4; ++ks)
            wf[t8][ks] = *(const i32x4*)(ws + WS_WFRAG + (((unsigned)(w * 8 + t8) * 4 + ks) << 10) + lane * 16);

    // B-frag read addr: wave covers banks 0..31 exactly once per ks -> zero conflicts
    int addrB[4];
#pragma unroll
    for (int ks = 0; ks < 4; ++ks)
        addrB[ks] = ks * 128 + cp * 64 + sg * 16;

    int k_own = w * 32 + mm * 16 + sg * 4 + 2 * X + cp;
    // packed h write: one dword per (gsel, mm, sg) covering k = base..base+3
    int addrW4 = (w >> 1) * 128 + gsel * 64 + ((w & 1) * 2 + mm) * 16 + sg * 4;
    int hsh = 8 * (2 * X + cp);                       // byte position in packed dword
    int biasP[2], wlv;
    {
        const int* bhh256 = (const int*)(ws + WS_BIASHH);
        int G0 = gsel, G1 = gsel + 2;
        biasP[0] = bhh256[G0 * 256 + k_own] + 768 * 256;                 // sigmoid pre-bias
        biasP[1] = bhh256[G1 * 256 + k_own] + (G1 == 2 ? 0 : 768 * 256); // G2 tanh: none
        wlv = ((const int*)(ws + WS_WLIN))[k_own];
    }
    size_t gioff = (size_t)((unsigned)wb * 8u + (unsigned)w) * 256u + (unsigned)lane * 4u;

    uint8_t* hst = ws + WS_HSTATE + (unsigned)wb * 512u;
    int* cst = (int*)(ws + WS_CSTATE) + (unsigned)wb * 512u + (unsigned)tid;

    int c_;
    if (t0 == 0) {
        c_ = 0;
        if (tid < 128) *(uint32_t*)(hb0 + tid * 4) = 0u;
    } else {
        c_ = *cst;
        if (tid < 128) *(uint32_t*)(hb0 + tid * 4) = *(const uint32_t*)(hst + tid * 4);
    }
    // prefetch gi for step 0 (stays in VGPRs across the barrier)
    int gcur = *(const int*)(ws + WS_GI + gioff);
    int gnx;
    __syncthreads();

    int hl_ = 0;
    const i32x4 zerov = {0, 0, 0, 0};

    // PLANEPAIR: u = acc[t8][2X], v = acc[t8][2X+1] with t8 = gsel?(mm?T3:T2):(mm?T1:T0)
#define PLANEPAIR(T0, T1, T2, T3, U, V)                                                \
    int U, V;                                                                          \
    {                                                                                  \
        int ua = X ? acc[T0][2] : acc[T0][0], va = X ? acc[T0][3] : acc[T0][1];        \
        int ub = X ? acc[T1][2] : acc[T1][0], vb = X ? acc[T1][3] : acc[T1][1];        \
        int uc = X ? acc[T2][2] : acc[T2][0], vc = X ? acc[T2][3] : acc[T2][1];        \
        int ud = X ? acc[T3][2] : acc[T3][0], vd = X ? acc[T3][3] : acc[T3][1];        \
        int u0 = mm ? ub : ua, v0 = mm ? vb : va;                                      \
        int u1 = mm ? ud : uc, v1 = mm ? vd : vc;                                      \
        U = gsel ? u1 : u0;                                                            \
        V = gsel ? v1 : v0;                                                            \
    }
    // SLOT: plane combine via partner lane^2 (DPP quad_perm, no DS); d = 4*a + b
#define SLOT(U, V, BIAS, OUTG)                                                         \
    int OUTG;                                                                          \
    {                                                                                  \
        int own = cp ? V : U;                                                          \
        int snd = cp ? U : V;                                                          \
        int z = DPPX2(snd);                                                            \
        int hi = cp ? z : own;                                                         \
        int lo = cp ? own : z;                                                         \
        OUTG = RHE8(hi * 4 + lo + (BIAS));                                             \
    }
    // Split-half schedule: tiles 0..3 (gA inputs) issue first; the whole gA path +
    // the gsel1 product p_f = RHE8(first*c_) execute between the halves, overlapping
    // the VALU work with half-2 MFMA issue/drain. Tail after last MFMA = gB path only.
#define STEP(PP, GUSE, GPRE, TPRE)                                                     \
    {                                                                                  \
        GPRE = *(const int*)(ws + WS_GI + (size_t)(TPRE) * 524288u + gioff);           \
        i32x4 bfv[4];                                                                  \
        _Pragma("unroll")                                                              \
        for (int ks = 0; ks < 4; ++ks)                                                 \
            bfv[ks] = *(const i32x4*)(hb0 + (PP) * 512 + addrB[ks]);                   \
        __builtin_amdgcn_s_setprio(1);                                                 \
        i32x4 acc[8];                                                                  \
        _Pragma("unroll")                                                              \
        for (int ks = 0; ks < 4; ++ks) {                                               \
            _Pragma("unroll")                                                          \
            for (int t8 = 0; t8 < 4; ++t8)                                             \
                acc[t8] = (ks == 0) ? MFMA_I8(wf[t8][0], bfv[0], zerov)                \
                                    : MFMA_I8(wf[t8][ks], bfv[ks], acc[t8]);           \
        }                                                                              \
        PLANEPAIR(0, 1, 2, 3, uA, vA)                                                  \
        SLOT(uA, vA, biasP[0], gA)                                                     \
        int givlo = ((GUSE) << 16) >> 16, givhi = (GUSE) >> 16;                        \
        int first = sigq(iclamp(gA + givlo, 0, 1536));        /* gsel0: i, gsel1: f */ \
        int p_f = RHE8(__mul24(first, c_));                   /* gsel1: fcq */         \
        _Pragma("unroll")                                                              \
        for (int ks = 0; ks < 4; ++ks) {                                               \
            _Pragma("unroll")                                                          \
            for (int t8 = 4; t8 < 8; ++t8)                                             \
                acc[t8] = (ks == 0) ? MFMA_I8(wf[t8][0], bfv[0], zerov)                \
                                    : MFMA_I8(wf[t8][ks], bfv[ks], acc[t8]);           \
        }                                                                              \
        __builtin_amdgcn_s_setprio(0);                                                 \
        PLANEPAIR(4, 5, 6, 7, uB, vB)                                                  \
        SLOT(uB, vB, biasP[1], gB)                                                     \
        int gBs = gB + givhi;                                                          \
        int sigB = sigq(iclamp(gBs, 0, 1536));                                         \
        int clpB = iclamp(gBs, -256, 256);                                             \
        int second = gsel ? sigB : clpB;                      /* gsel0: c_g, gsel1: o */ \
        int p_i = RHE8(__mul24(first, second));               /* gsel0: icq */         \
        int ownp = gsel ? p_f : p_i;                                                   \
        int othp = DPPX1(ownp);                                                        \
        int cn  = iclamp(ownp + othp, -32768, 32767);                                  \
        c_ = cn;                                                                       \
        int th = iclamp(cn, -256, 256);                                                \
        int hq1 = RHE8(__mul24(second, th));                  /* valid in gsel=1 */    \
        int hqp = DPPX1(hq1);                                                          \
        int hq = gsel ? hq1 : hqp;                                                     \
        /* packed dword write: gather 4 plane-bytes (k offsets 2X+cp) via DPP */       \
        unsigned hby = (unsigned)(gsel ? (hq & 3) : (hq >> 2)) & 255u;                 \
        unsigned pv = hby << hsh;                                                      \
        pv |= (unsigned)DPPX2((int)pv);                                                \
        pv |= (unsigned)DPPROR8((int)pv);                                              \
        if ((lane & 10) == 0)                                                          \
            *(uint32_t*)(hb0 + ((PP) ^ 1) * 512 + addrW4) = pv;                        \
        hl_ = hq;                                                                      \
        BAR();                                                                         \
    }

    for (int tl = 0; tl < cs; tl += 2) {
        int tn2 = (tl + 2 < cs) ? tl + 2 : 0;   // harmless wrap on last iter
        STEP(0, gcur, gnx, tl + 1)
        STEP(1, gnx, gcur, tn2)
    }
#undef STEP
#undef SLOT
#undef PLANEPAIR

    // save state for next chunk (final buffer parity is 0 since cs is even)
    if (tid < 128) *(uint32_t*)(hst + tid * 4) = *(const uint32_t*)(hb0 + tid * 4);
    *cst = c_;

    if (t0 + cs == 512) {   // head: out = quant(h_last @ w_lin^T + b_lin), exact int64
        long long s = gsel ? 0LL : (long long)hl_ * (long long)wlv;
        s += __shfl_xor(s, 1);
        s += __shfl_xor(s, 2);
        s += __shfl_xor(s, 4);
        s += __shfl_xor(s, 8);
        s += __shfl_xor(s, 16);
        s += __shfl_xor(s, 32);
        if (lane == 0) redl[w] = s;
        __syncthreads();
        if (tid == 0) {
            long long tot = 0;
#pragma unroll
            for (int ww = 0; ww < 8; ++ww) tot += redl[ww];
            tot += 256LL * (long long)((const int*)(ws + WS_BLIN))[0];
            long long q = ((tot + 127) + ((tot >> 8) & 1)) >> 8;
            q = q < -32768 ? -32768 : (q > 32767 ? 32767 : q);
            out[wb] = (float)q * 0.00390625f;
        }
    }
}

// ---------------- host ----------------
extern "C" void kernel_launch(void* const* d_in, const int* in_sizes, int n_in,
                              void* d_out, int out_size, void* d_ws, size_t ws_size,
                              hipStream_t stream) {
    const float* x    = (const float*)d_in[0];
    const float* wih  = (const float*)d_in[1];
    const float* whh  = (const float*)d_in[2];
    const float* bih  = (const float*)d_in[3];
    const float* bhh  = (const float*)d_in[4];
    const float* wlin = (const float*)d_in[5];
    const float* blin = (const float*)d_in[6];
    float* out = (float*)d_out;
    uint8_t* ws = (uint8_t*)d_ws;

    prep_kernel<<<512, 512, 0, stream>>>(wih, whh, bih, bhh, wlin, blin, ws);

    int cs = 512;
    while ((size_t)WS_GI + (size_t)cs * 524288u > ws_size && cs > 8) cs >>= 1;

    for (int t0 = 0; t0 < 512; t0 += cs) {
        gi_kernel<<<dim3(16, cs / 4), 512, 0, stream>>>(x, ws, t0);
        recur_kernel<<<256, 512, 0, stream>>>(ws, out, t0, cs);
    }
}